// Round 1
// 6060.016 us; speedup vs baseline: 1.0270x; 1.0270x over previous
//
#include <hip/hip_runtime.h>
#include <hip/hip_bf16.h>
#include <math.h>

#define NF 50000
#define NFP 50048
#define NV 1024
#define NA 64
#define NSLICE 25
#define SCALE_QK 0.088388347648318447f

// ---------------- ws layout (bytes) ----------------
static const size_t OFF_K    = 0;                                   // float [NFP*128]
static const size_t OFF_V    = OFF_K   + (size_t)NFP*128*4;         // float [NFP*128]
static const size_t OFF_P    = OFF_V   + (size_t)NFP*128*4;         // bf16  [NV*NFP]
static const size_t OFF_H    = OFF_P   + (size_t)NV*NFP*2;          // float [NV*128]
static const size_t OFF_Q    = OFF_H   + (size_t)NV*128*4;          // float [NV*128]
static const size_t OFF_PART = OFF_Q   + (size_t)NV*128*4;          // float [25*NV*128]
static const size_t OFF_ACC  = OFF_PART+ (size_t)NSLICE*NV*128*4;   // float Z,Zl,Yp,Yl [4*1024] + avg[3*1024]
static const size_t OFF_CNT  = OFF_ACC + 28672;                     // float [64]
static const size_t OFF_CTR  = OFF_CNT + 256;                       // (unused, legacy)

// Grid-barrier flags overlay the head of the P buffer: P is dead between
// gate_kern (last reader: pv_kern) and the next scores_kern (full rewrite).
// 64 arrival words (stride 8 uints = 32B) + 8 release copies. 2304 bytes,
// memset to 0 before each cooc launch; epochs count 1..NA within a launch.

// ---------------- helpers ----------------
__device__ __forceinline__ float bflo(unsigned w){ union{unsigned u;float f;}c; c.u=w<<16; return c.f; }
__device__ __forceinline__ float bfhi(unsigned w){ union{unsigned u;float f;}c; c.u=w&0xffff0000u; return c.f; }
__device__ __forceinline__ unsigned short f2bf(float x){ __hip_bfloat16 b=__float2bfloat16(x); return *(unsigned short*)&b; }
__device__ __forceinline__ float geluf(float x){ return 0.5f*x*(1.0f+erff(x*0.70710678118654752f)); }
__device__ __forceinline__ float sigmf(float x){ return 1.0f/(1.0f+__expf(-x)); }

// Aggregator grid barrier, zero RMW:
//  - every block stores monotonic epoch to its OWN flag line (1 writer/1 reader per line)
//  - block 0 wave 0 polls all 64 flags (sole reader of each), then stores the
//    release epoch replicated on 8 lines; blocks poll copy (bid&7) -> <=8 readers/line.
// Visibility: the leading __syncthreads() emits s_waitcnt vmcnt(0), so all prior
// global atomics (seed adds) are complete at L3 before the arrival store issues.
__device__ __forceinline__ void gridbar2(unsigned* __restrict__ barr, int bid, int t, unsigned ep){
  __syncthreads();
  if (t==0)
    __hip_atomic_store(&barr[bid<<3], ep, __ATOMIC_RELAXED, __HIP_MEMORY_SCOPE_AGENT);
  if (bid==0){
    if (t<64){
      while (__hip_atomic_load(&barr[t<<3], __ATOMIC_RELAXED, __HIP_MEMORY_SCOPE_AGENT) < ep)
        __builtin_amdgcn_s_sleep(1);
    }
    __syncthreads();
    if (t<8)
      __hip_atomic_store(&barr[512+(t<<3)], ep, __ATOMIC_RELAXED, __HIP_MEMORY_SCOPE_AGENT);
  } else if (t==0){
    while (__hip_atomic_load(&barr[512+((bid&7)<<3)], __ATOMIC_RELAXED, __HIP_MEMORY_SCOPE_AGENT) < ep)
      __builtin_amdgcn_s_sleep(1);
  }
  __syncthreads();
}

// ---------------- cnt per atom ----------------
__global__ __launch_bounds__(256) void cnt_kern(const int* __restrict__ cm, float* __restrict__ cntf){
  __shared__ int sd[256];
  const int a=blockIdx.x, t=threadIdx.x;
  int s=0;
  for (int i=t;i<NV;i+=256) s+=cm[a*NV+i];
  sd[t]=s; __syncthreads();
  for (int o=128;o>0;o>>=1){ if(t<o) sd[t]+=sd[t+o]; __syncthreads(); }
  if (t==0) cntf[a]=(float)sd[0];
}

// ---------------- K/V projection: (NFP x 128) = fe @ W + b ----------------
__global__ __launch_bounds__(256)
void kvproj_kern(const float* __restrict__ fe,
                 const float* __restrict__ Wk, const float* __restrict__ bk,
                 const float* __restrict__ Wv, const float* __restrict__ bv,
                 float* __restrict__ Kout, float* __restrict__ Vout){
  __shared__ float As[32][68];
  __shared__ float Bs[32][132];
  const int t=threadIdx.x;
  const int f0=blockIdx.x*64;
  const float* W  = blockIdx.y ? Wv : Wk;
  const float* bb = blockIdx.y ? bv : bk;
  float* Out      = blockIdx.y ? Vout : Kout;
  float acc[4][8];
  #pragma unroll
  for(int i=0;i<4;i++){ for(int j=0;j<8;j++) acc[i][j]=0.f; }
  for (int kc=0;kc<128;kc+=32){
    { const int floc=t>>2, koff=(t&3)*8; const int f=f0+floc;
      if (f<NF){
        const float* src=fe+((size_t)f<<7)+kc+koff;
        float4 a=*(const float4*)src, b=*(const float4*)(src+4);
        As[koff+0][floc]=a.x; As[koff+1][floc]=a.y; As[koff+2][floc]=a.z; As[koff+3][floc]=a.w;
        As[koff+4][floc]=b.x; As[koff+5][floc]=b.y; As[koff+6][floc]=b.z; As[koff+7][floc]=b.w;
      } else { for(int i=0;i<8;i++) As[koff+i][floc]=0.f; } }
    { const int kk=t>>3, coff=(t&7)*16;
      const float* src=W+((size_t)(kc+kk)<<7)+coff;
      float4 a=*(const float4*)src, b=*(const float4*)(src+4), c=*(const float4*)(src+8), d=*(const float4*)(src+12);
      Bs[kk][coff+0]=a.x;Bs[kk][coff+1]=a.y;Bs[kk][coff+2]=a.z;Bs[kk][coff+3]=a.w;
      Bs[kk][coff+4]=b.x;Bs[kk][coff+5]=b.y;Bs[kk][coff+6]=b.z;Bs[kk][coff+7]=b.w;
      Bs[kk][coff+8]=c.x;Bs[kk][coff+9]=c.y;Bs[kk][coff+10]=c.z;Bs[kk][coff+11]=c.w;
      Bs[kk][coff+12]=d.x;Bs[kk][coff+13]=d.y;Bs[kk][coff+14]=d.z;Bs[kk][coff+15]=d.w; }
    __syncthreads();
    const int mloc=(t&15)*4, nloc=(t>>4)*8;
    #pragma unroll
    for (int kk=0;kk<32;kk++){
      const float4 a=*(const float4*)&As[kk][mloc];
      const float4 b0=*(const float4*)&Bs[kk][nloc];
      const float4 b1=*(const float4*)&Bs[kk][nloc+4];
      const float am[4]={a.x,a.y,a.z,a.w};
      const float bn[8]={b0.x,b0.y,b0.z,b0.w,b1.x,b1.y,b1.z,b1.w};
      #pragma unroll
      for(int mi=0;mi<4;mi++){
        #pragma unroll
        for(int ni=0;ni<8;ni++) acc[mi][ni]=fmaf(am[mi],bn[ni],acc[mi][ni]);
      }
    }
    __syncthreads();
  }
  const int mloc=(t&15)*4, nloc=(t>>4)*8;
  #pragma unroll
  for(int mi=0;mi<4;mi++){
    const int f=f0+mloc+mi;
    float o[8];
    #pragma unroll
    for(int ni=0;ni<8;ni++) o[ni]=(f<NF)? (acc[mi][ni]+bb[nloc+ni]) : 0.f;
    float* dst=Out+((size_t)f<<7)+nloc;
    *(float4*)dst     = make_float4(o[0],o[1],o[2],o[3]);
    *(float4*)(dst+4) = make_float4(o[4],o[5],o[6],o[7]);
  }
}

// ---------------- q = h @ Wq + bq ----------------
__global__ __launch_bounds__(128)
void qproj_kern(const float* __restrict__ h, const float* __restrict__ Wq,
                const float* __restrict__ bq, float* __restrict__ q){
  __shared__ float hs[128];
  const int v=blockIdx.x, c=threadIdx.x;
  hs[c]=h[(v<<7)+c];
  __syncthreads();
  float acc=bq[c];
  #pragma unroll 8
  for (int k=0;k<128;k++) acc=fmaf(hs[k],Wq[(k<<7)+c],acc);
  q[(v<<7)+c]=acc;
}

// ---------------- scores: P = exp(scale*q.K^T) (bf16), + row sums ----------------
template<int FINAL>
__global__ __launch_bounds__(256)
void scores_kern(const float* __restrict__ qb, const float* __restrict__ Kb,
                 const float* __restrict__ gum, unsigned short* __restrict__ Pb,
                 float* __restrict__ accg){
  __shared__ float As[32][68];
  __shared__ float Bs[32][132];
  __shared__ float Zs[64], Zls[64], Yps[64], Yls[64];
  const int t=threadIdx.x;
  const int f0=blockIdx.x*128;
  const int v0=blockIdx.y*64;
  float acc[4][8];
  #pragma unroll
  for(int i=0;i<4;i++){ for(int j=0;j<8;j++) acc[i][j]=0.f; }
  if (t<64){ Zs[t]=0.f; if(FINAL){ Zls[t]=0.f; Yps[t]=0.f; Yls[t]=0.f; } }
  for (int kc=0;kc<128;kc+=32){
    { const int vloc=t>>2, koff=(t&3)*8;
      const float* src=qb+((size_t)(v0+vloc)<<7)+kc+koff;
      float4 a=*(const float4*)src, b=*(const float4*)(src+4);
      As[koff+0][vloc]=a.x; As[koff+1][vloc]=a.y; As[koff+2][vloc]=a.z; As[koff+3][vloc]=a.w;
      As[koff+4][vloc]=b.x; As[koff+5][vloc]=b.y; As[koff+6][vloc]=b.z; As[koff+7][vloc]=b.w; }
    { const int floc=t>>1, koff=(t&1)*16; const int f=f0+floc;
      if (f<NF){
        const float* src=Kb+((size_t)f<<7)+kc+koff;
        float4 a=*(const float4*)src, b=*(const float4*)(src+4), c=*(const float4*)(src+8), d=*(const float4*)(src+12);
        Bs[koff+0][floc]=a.x;Bs[koff+1][floc]=a.y;Bs[koff+2][floc]=a.z;Bs[koff+3][floc]=a.w;
        Bs[koff+4][floc]=b.x;Bs[koff+5][floc]=b.y;Bs[koff+6][floc]=b.z;Bs[koff+7][floc]=b.w;
        Bs[koff+8][floc]=c.x;Bs[koff+9][floc]=c.y;Bs[koff+10][floc]=c.z;Bs[koff+11][floc]=c.w;
        Bs[koff+12][floc]=d.x;Bs[koff+13][floc]=d.y;Bs[koff+14][floc]=d.z;Bs[koff+15][floc]=d.w;
      } else { for(int i=0;i<16;i++) Bs[koff+i][floc]=0.f; } }
    __syncthreads();
    const int mloc=(t&15)*4, nloc=(t>>4)*8;
    #pragma unroll
    for (int kk=0;kk<32;kk++){
      const float4 a=*(const float4*)&As[kk][mloc];
      const float4 b0=*(const float4*)&Bs[kk][nloc];
      const float4 b1=*(const float4*)&Bs[kk][nloc+4];
      const float am[4]={a.x,a.y,a.z,a.w};
      const float bn[8]={b0.x,b0.y,b0.z,b0.w,b1.x,b1.y,b1.z,b1.w};
      #pragma unroll
      for(int mi=0;mi<4;mi++){
        #pragma unroll
        for(int ni=0;ni<8;ni++) acc[mi][ni]=fmaf(am[mi],bn[ni],acc[mi][ni]);
      }
    }
    __syncthreads();
  }
  const int mloc=(t&15)*4, nloc=(t>>4)*8;
  #pragma unroll
  for(int mi=0;mi<4;mi++){
    const int v=v0+mloc+mi;
    float zp=0.f, zl=0.f, yp=0.f, yl=0.f;
    float uu[8];
    if (FINAL){
      const int fbase=f0+nloc;
      if (fbase+8<=NF){
        const float* gsrc=gum+(size_t)v*NF+fbase;
        float4 g0=*(const float4*)gsrc, g1=*(const float4*)(gsrc+4);
        uu[0]=g0.x;uu[1]=g0.y;uu[2]=g0.z;uu[3]=g0.w;uu[4]=g1.x;uu[5]=g1.y;uu[6]=g1.z;uu[7]=g1.w;
      } else {
        for(int i=0;i<8;i++){ int f=fbase+i; uu[i]=(f<NF)? gum[(size_t)v*NF+f] : 0.5f; }
      }
    }
    unsigned short pr[8];
    #pragma unroll
    for(int ni=0;ni<8;ni++){
      const int f=f0+nloc+ni;
      const float s=acc[mi][ni]*SCALE_QK;
      float pv_=0.f;
      if (f<NF){
        const float ep=__expf(s);
        if (FINAL){
          const float g=-__logf(-__logf(uu[ni]));
          const float el=__expf(2.0f*(s+g));
          pv_=el; zl+=el; yl+=el*s; zp+=ep; yp+=ep*s;
        } else { pv_=ep; zp+=ep; }
      }
      pr[ni]=f2bf(pv_);
    }
    uint4 pk;
    pk.x=(unsigned)pr[0]|((unsigned)pr[1]<<16);
    pk.y=(unsigned)pr[2]|((unsigned)pr[3]<<16);
    pk.z=(unsigned)pr[4]|((unsigned)pr[5]<<16);
    pk.w=(unsigned)pr[6]|((unsigned)pr[7]<<16);
    *(uint4*)(Pb+(size_t)v*NFP+f0+nloc)=pk;
    atomicAdd(&Zs[mloc+mi],zp);
    if (FINAL){ atomicAdd(&Zls[mloc+mi],zl); atomicAdd(&Yps[mloc+mi],yp); atomicAdd(&Yls[mloc+mi],yl); }
  }
  __syncthreads();
  if (t<64){
    atomicAdd(&accg[v0+t],Zs[t]);
    if (FINAL){
      atomicAdd(&accg[1024+v0+t],Zls[t]);
      atomicAdd(&accg[2048+v0+t],Yps[t]);
      atomicAdd(&accg[3072+v0+t],Yls[t]);
    }
  }
}

// ---------------- PV: partial[slice] = P_slice @ V_slice ----------------
__global__ __launch_bounds__(256)
void pv_kern(const unsigned short* __restrict__ Pb, const float* __restrict__ Vb,
             float* __restrict__ part){
  __shared__ float As[32][68];
  __shared__ float Bs[32][132];
  const int t=threadIdx.x;
  const int slice=blockIdx.x;
  const int v0=blockIdx.y*64;
  const int fbeg=slice*2048;
  const int fend=min(fbeg+2048,(int)NFP);
  float acc[4][8];
  #pragma unroll
  for(int i=0;i<4;i++){ for(int j=0;j<8;j++) acc[i][j]=0.f; }
  for (int fc=fbeg; fc<fend; fc+=32){
    { const int vloc=t>>2, koff=(t&3)*8;
      const unsigned short* src=Pb+(size_t)(v0+vloc)*NFP+fc+koff;
      uint4 r=*(const uint4*)src;
      As[koff+0][vloc]=bflo(r.x); As[koff+1][vloc]=bfhi(r.x);
      As[koff+2][vloc]=bflo(r.y); As[koff+3][vloc]=bfhi(r.y);
      As[koff+4][vloc]=bflo(r.z); As[koff+5][vloc]=bfhi(r.z);
      As[koff+6][vloc]=bflo(r.w); As[koff+7][vloc]=bfhi(r.w); }
    { const int kk=t>>3, doff=(t&7)*16;
      const float* src=Vb+((size_t)(fc+kk)<<7)+doff;
      float4 a=*(const float4*)src, b=*(const float4*)(src+4), c=*(const float4*)(src+8), d=*(const float4*)(src+12);
      Bs[kk][doff+0]=a.x;Bs[kk][doff+1]=a.y;Bs[kk][doff+2]=a.z;Bs[kk][doff+3]=a.w;
      Bs[kk][doff+4]=b.x;Bs[kk][doff+5]=b.y;Bs[kk][doff+6]=b.z;Bs[kk][doff+7]=b.w;
      Bs[kk][doff+8]=c.x;Bs[kk][doff+9]=c.y;Bs[kk][doff+10]=c.z;Bs[kk][doff+11]=c.w;
      Bs[kk][doff+12]=d.x;Bs[kk][doff+13]=d.y;Bs[kk][doff+14]=d.z;Bs[kk][doff+15]=d.w; }
    __syncthreads();
    const int mloc=(t&15)*4, nloc=(t>>4)*8;
    #pragma unroll
    for (int kk=0;kk<32;kk++){
      const float4 a=*(const float4*)&As[kk][mloc];
      const float4 b0=*(const float4*)&Bs[kk][nloc];
      const float4 b1=*(const float4*)&Bs[kk][nloc+4];
      const float am[4]={a.x,a.y,a.z,a.w};
      const float bn[8]={b0.x,b0.y,b0.z,b0.w,b1.x,b1.y,b1.z,b1.w};
      #pragma unroll
      for(int mi=0;mi<4;mi++){
        #pragma unroll
        for(int ni=0;ni<8;ni++) acc[mi][ni]=fmaf(am[mi],bn[ni],acc[mi][ni]);
      }
    }
    __syncthreads();
  }
  const int mloc=(t&15)*4, nloc=(t>>4)*8;
  #pragma unroll
  for(int mi=0;mi<4;mi++){
    const int v=v0+mloc+mi;
    float* dst=part+(((size_t)slice*NV+v)<<7)+nloc;
    *(float4*)dst     = make_float4(acc[mi][0],acc[mi][1],acc[mi][2],acc[mi][3]);
    *(float4*)(dst+4) = make_float4(acc[mi][4],acc[mi][5],acc[mi][6],acc[mi][7]);
  }
}

// ---------------- main-loop gate update ----------------
__global__ __launch_bounds__(256)
void gate_kern(float* __restrict__ h, const float* __restrict__ part, const float* __restrict__ Z,
               const float* __restrict__ Wm1, const float* __restrict__ bm1,
               const float* __restrict__ Wm2, const float* __restrict__ bm2){
  const int t=threadIdx.x, w=t>>6, lane=t&63;
  const int v=(blockIdx.x<<2)+w;
  const float h0=h[(v<<7)+lane], h1=h[(v<<7)+64+lane];
  const float zr=1.0f/Z[v];
  float c0=0.f,c1=0.f;
  for (int s=0;s<NSLICE;s++){
    c0+=part[(((size_t)s*NV+v)<<7)+lane];
    c1+=part[(((size_t)s*NV+v)<<7)+64+lane];
  }
  c0*=zr; c1*=zr;
  float y0=bm1[lane], y1=bm1[64+lane];
  for (int k=0;k<64;k++){ const float a=__shfl(h0,k); y0=fmaf(a,Wm1[(k<<7)+lane],y0);      y1=fmaf(a,Wm1[(k<<7)+64+lane],y1); }
  for (int k=0;k<64;k++){ const float a=__shfl(h1,k); y0=fmaf(a,Wm1[((64+k)<<7)+lane],y0); y1=fmaf(a,Wm1[((64+k)<<7)+64+lane],y1); }
  for (int k=0;k<64;k++){ const float a=__shfl(c0,k); y0=fmaf(a,Wm1[((128+k)<<7)+lane],y0);y1=fmaf(a,Wm1[((128+k)<<7)+64+lane],y1); }
  for (int k=0;k<64;k++){ const float a=__shfl(c1,k); y0=fmaf(a,Wm1[((192+k)<<7)+lane],y0);y1=fmaf(a,Wm1[((192+k)<<7)+64+lane],y1); }
  y0=geluf(y0); y1=geluf(y1);
  float z0=bm2[lane], z1=bm2[64+lane];
  for (int k=0;k<64;k++){ const float a=__shfl(y0,k); z0=fmaf(a,Wm2[(k<<7)+lane],z0);      z1=fmaf(a,Wm2[(k<<7)+64+lane],z1); }
  for (int k=0;k<64;k++){ const float a=__shfl(y1,k); z0=fmaf(a,Wm2[((64+k)<<7)+lane],z0); z1=fmaf(a,Wm2[((64+k)<<7)+64+lane],z1); }
  const float g0=sigmf(z0), g1=sigmf(z1);
  h[(v<<7)+lane]   = fmaf(g0,c0-h0,h0);
  h[(v<<7)+64+lane]= fmaf(g1,c1-h1,h1);
}

// ---------------- cooc scan (persistent, 64 blocks x 1024 thr) ----------------
// Per-atom grid sync via aggregator barrier (gridbar2). Per-wave atom-membership
// bitmask (ballot over cm column) removes per-atom cm loads from critical path;
// cnt staged in LDS.
__global__ __launch_bounds__(1024,4)
void cooc_kern(float* __restrict__ h, const int* __restrict__ cm, const float* __restrict__ cntf,
               const float* __restrict__ Wc1, const float* __restrict__ bc1,
               const float* __restrict__ Wc2, const float* __restrict__ bc2,
               float* __restrict__ bufs, unsigned* __restrict__ barr){
  __shared__ unsigned W1s[128*64];   // bf16 pairs (c, c+64), Wc1 rows 0..127 (h-part)
  __shared__ unsigned W2s[104*64];   // bf16 pairs, Wc2 rows 0..103 (rest from global)
  __shared__ float ypart[1024];      // 8 k-segments x 128 outputs for avg@Wc1
  __shared__ float avgs[128];
  __shared__ float yavs[128];
  __shared__ float seedb[128];
  __shared__ float cnts[64];
  __shared__ int   anyf;
  const int t=threadIdx.x, w=t>>6, lane=t&63;
  const int bid=blockIdx.x;
  const int v=(bid<<4)+w;
  const int stripe=bid&7;
  for (int i=t;i<128*64;i+=1024){ const int k=i>>6,l=i&63;
    W1s[i]=(unsigned)f2bf(Wc1[(k<<7)+l])|(((unsigned)f2bf(Wc1[(k<<7)+64+l]))<<16); }
  for (int i=t;i<104*64;i+=1024){ const int k=i>>6,l=i&63;
    W2s[i]=(unsigned)f2bf(Wc2[(k<<7)+l])|(((unsigned)f2bf(Wc2[(k<<7)+64+l]))<<16); }
  if (t<64) cnts[t]=cntf[t];
  // bit a of amask = (cm[a*NV+v] != 0); NA==64 == wave width
  const unsigned long long amask=__ballot(cm[lane*NV+v]!=0);
  float h0=h[(v<<7)+lane], h1=h[(v<<7)+64+lane];
  const float b10=bc1[lane], b11=bc1[64+lane];
  const float b20=bc2[lane], b21=bc2[64+lane];
  // ---- seed atom 0 (bufs pre-zeroed by host memset) ----
  if (t<128) seedb[t]=0.f;
  if (t==0) anyf=0;
  __syncthreads();
  if (amask&1ull){ atomicAdd(&seedb[lane],h0); atomicAdd(&seedb[64+lane],h1); if(lane==0) anyf=1; }
  __syncthreads();
  if (anyf && t<128) atomicAdd(&bufs[(stripe<<7)+t],seedb[t]);
  unsigned ep=0;
  gridbar2(barr,bid,t,++ep);
  for (int a=0;a<NA;a++){
    const int cur=a%3, nxt=(a+1)%3, zz=(a+2)%3;
    const float cf=cnts[a];
    // ---- read striped sum -> avgs ----
    if (t<128){
      float s=0.f;
      #pragma unroll
      for (int sp=0;sp<8;sp++)
        s+=__hip_atomic_load(&bufs[(cur<<10)+(sp<<7)+t],__ATOMIC_RELAXED,__HIP_MEMORY_SCOPE_AGENT);
      avgs[t]=s/fmaxf(cf,1.0f);
    }
    if (bid==0)
      __hip_atomic_store(&bufs[(zz<<10)+t],0.0f,__ATOMIC_RELAXED,__HIP_MEMORY_SCOPE_AGENT);
    __syncthreads();
    // ---- yavs = avgs @ Wc1[128:256,:]  (split over 8 k-segments, all 16 waves) ----
    { const int seg=t>>7, ok=t&127;
      const int kb=seg<<4;
      float s=0.f;
      #pragma unroll
      for (int j=0;j<16;j++) s=fmaf(avgs[kb+j],Wc1[((128+kb+j)<<7)+ok],s);
      ypart[(seg<<7)+ok]=s; }
    __syncthreads();
    if (t<128){
      float s=0.f;
      #pragma unroll
      for (int seg=0;seg<8;seg++) s+=ypart[(seg<<7)+t];
      yavs[t]=s;
    } else if (t<256) seedb[t-128]=0.f;
    else if (t==256) anyf=0;
    __syncthreads();
    // ---- gate update (1 var per wave) ----
    const bool act=((amask>>a)&1ull)&&(cf>=2.0f);
    if (act){
      const float av0=avgs[lane], av1=avgs[64+lane];
      float y0=b10+yavs[lane], y1=b11+yavs[64+lane];
      #pragma unroll 8
      for (int k=0;k<64;k++){ const float hk=__shfl(h0,k); const unsigned wp=W1s[(k<<6)+lane];
        y0=fmaf(hk,bflo(wp),y0); y1=fmaf(hk,bfhi(wp),y1); }
      #pragma unroll 8
      for (int k=0;k<64;k++){ const float hk=__shfl(h1,k); const unsigned wp=W1s[((64+k)<<6)+lane];
        y0=fmaf(hk,bflo(wp),y0); y1=fmaf(hk,bfhi(wp),y1); }
      y0=geluf(y0); y1=geluf(y1);
      float z0=b20, z1=b21;
      #pragma unroll 8
      for (int k=0;k<64;k++){ const float yk=__shfl(y0,k); const unsigned wp=W2s[(k<<6)+lane];
        z0=fmaf(yk,bflo(wp),z0); z1=fmaf(yk,bfhi(wp),z1); }
      #pragma unroll 8
      for (int k=0;k<40;k++){ const float yk=__shfl(y1,k); const unsigned wp=W2s[((64+k)<<6)+lane];
        z0=fmaf(yk,bflo(wp),z0); z1=fmaf(yk,bfhi(wp),z1); }
      for (int k=40;k<64;k++){ const float yk=__shfl(y1,k);
        z0=fmaf(yk,Wc2[((64+k)<<7)+lane],z0); z1=fmaf(yk,Wc2[((64+k)<<7)+64+lane],z1); }
      const float g0=sigmf(z0), g1=sigmf(z1);
      h0=fmaf(g0,av0-h0,h0); h1=fmaf(g1,av1-h1,h1);
    }
    // ---- block-aggregated seed for atom a+1 ----
    if (a<NA-1){
      if ((amask>>(a+1))&1ull){
        atomicAdd(&seedb[lane],h0); atomicAdd(&seedb[64+lane],h1);
        if (lane==0) anyf=1;
      }
      __syncthreads();
      if (anyf && t<128)
        atomicAdd(&bufs[(nxt<<10)+(stripe<<7)+t],seedb[t]);
      gridbar2(barr,bid,t,++ep);
    }
  }
  h[(v<<7)+lane]=h0; h[(v<<7)+64+lane]=h1;
}

// ---------------- final write-out ----------------
__global__ __launch_bounds__(256)
void writeout_kern(const float* __restrict__ accg, const float* __restrict__ part,
                   float* __restrict__ out){
  const int b=blockIdx.x, t=threadIdx.x;
  const int v0=b*16;
  for (int i=t;i<16*128;i+=256){
    const int v=v0+(i>>7), d=i&127;
    float s=0.f;
    for (int sl=0;sl<NSLICE;sl++) s+=part[(((size_t)sl*NV+v)<<7)+d];
    out[1+((size_t)v<<7)+d]=s/accg[1024+v];
  }
  __shared__ float es[16], hsv[16];
  if (t<16){
    const int v=v0+t;
    const float Zp=accg[v], Zl=accg[1024+v], Yp=accg[2048+v], Yl=accg[3072+v];
    es[t]=-Yl/Zl;
    hsv[t]=-(Yp/Zp-logf(Zp));
  }
  __syncthreads();
  if (t==0){
    float a=0.f,c=0.f;
    for(int i=0;i<16;i++){ a+=es[i]; c+=hsv[i]; }
    atomicAdd(&out[0],a);
    atomicAdd(&out[1+(size_t)NV*128],c);
  }
}

// ---------------- host ----------------
extern "C" void kernel_launch(void* const* d_in, const int* in_sizes, int n_in,
                              void* d_out, int out_size, void* d_ws, size_t ws_size,
                              hipStream_t stream){
  (void)in_sizes; (void)n_in; (void)ws_size;
  const float* fe =(const float*)d_in[0];
  const float* vi =(const float*)d_in[1];
  const int*   cm =(const int*)  d_in[2];
  const float* gum=(const float*)d_in[3];
  const float* Wq =(const float*)d_in[4];  const float* bq =(const float*)d_in[5];
  const float* Wk =(const float*)d_in[6];  const float* bk =(const float*)d_in[7];
  const float* Wv =(const float*)d_in[8];  const float* bv =(const float*)d_in[9];
  const float* Wm1=(const float*)d_in[10]; const float* bm1=(const float*)d_in[11];
  const float* Wm2=(const float*)d_in[12]; const float* bm2=(const float*)d_in[13];
  const float* Wc1=(const float*)d_in[14]; const float* bc1=(const float*)d_in[15];
  const float* Wc2=(const float*)d_in[16]; const float* bc2=(const float*)d_in[17];
  float* out=(float*)d_out;
  char* w8=(char*)d_ws;
  float* Kb=(float*)(w8+OFF_K);
  float* Vb=(float*)(w8+OFF_V);
  unsigned short* Pb=(unsigned short*)(w8+OFF_P);
  float* hb=(float*)(w8+OFF_H);
  float* qb=(float*)(w8+OFF_Q);
  float* part=(float*)(w8+OFF_PART);
  float* accb=(float*)(w8+OFF_ACC);
  float* avgb=accb+4096;
  float* cntf=(float*)(w8+OFF_CNT);
  // barrier flags overlay the head of the (dead-at-cooc-time) P buffer
  unsigned* barr=(unsigned*)(w8+OFF_P);

  hipMemsetAsync(out,0,(size_t)out_size*4,stream);
  hipMemcpyAsync(hb,vi,(size_t)NV*128*4,hipMemcpyDeviceToDevice,stream);
  cnt_kern<<<NA,256,0,stream>>>(cm,cntf);
  kvproj_kern<<<dim3(NFP/64,2),256,0,stream>>>(fe,Wk,bk,Wv,bv,Kb,Vb);

  for (int it=0; it<3; it++){
    hipMemsetAsync(accb,0,28672,stream);
    qproj_kern<<<NV,128,0,stream>>>(hb,Wq,bq,qb);
    scores_kern<0><<<dim3(NFP/128,16),256,0,stream>>>(qb,Kb,nullptr,Pb,accb);
    pv_kern<<<dim3(NSLICE,16),256,0,stream>>>(Pb,Vb,part);
    gate_kern<<<NV/4,256,0,stream>>>(hb,part,accb,Wm1,bm1,Wm2,bm2);
    hipMemsetAsync(barr,0,2304,stream);   // P dead here; rewritten by next scores_kern
    cooc_kern<<<64,1024,0,stream>>>(hb,cm,cntf,Wc1,bc1,Wc2,bc2,avgb,barr);
  }

  hipMemsetAsync(accb,0,28672,stream);
  qproj_kern<<<NV,128,0,stream>>>(hb,Wq,bq,qb);
  scores_kern<1><<<dim3(NFP/128,16),256,0,stream>>>(qb,Kb,gum,Pb,accb);
  pv_kern<<<dim3(NSLICE,16),256,0,stream>>>(Pb,Vb,part);
  writeout_kern<<<64,256,0,stream>>>(accb,part,out);
}

// Round 2
// 5577.660 us; speedup vs baseline: 1.1158x; 1.0865x over previous
//
#include <hip/hip_runtime.h>
#include <hip/hip_bf16.h>
#include <math.h>

#define NF 50000
#define NFP 50048
#define NV 1024
#define NA 64
#define NSLICE 25
#define SCALE_QK 0.088388347648318447f

// ---------------- ws layout (bytes) ----------------
// bf16 split buffers replace fp32 K/V; footprint identical to previous (167.93 MB)
static const size_t OFF_KH   = 0;                                    // ushort [NFP*128]
static const size_t OFF_KL   = OFF_KH  + (size_t)NFP*128*2;          // ushort [NFP*128]
static const size_t OFF_VTH  = OFF_KL  + (size_t)NFP*128*2;          // ushort [128*NFP] (transposed)
static const size_t OFF_VTL  = OFF_VTH + (size_t)128*NFP*2;          // ushort [128*NFP]
static const size_t OFF_P    = OFF_VTL + (size_t)128*NFP*2;          // bf16  [NV*NFP]
static const size_t OFF_H    = OFF_P   + (size_t)NV*NFP*2;           // float [NV*128]
static const size_t OFF_QH   = OFF_H   + (size_t)NV*128*4;           // ushort[NV*128]
static const size_t OFF_QL   = OFF_QH  + (size_t)NV*128*2;           // ushort[NV*128]
static const size_t OFF_PART = OFF_QL  + (size_t)NV*128*2;           // float [25*NV*128]
static const size_t OFF_ACC  = OFF_PART+ (size_t)NSLICE*NV*128*4;    // float Z,Zl,Yp,Yl [4*1024] + avg[3*1024]
static const size_t OFF_CNT  = OFF_ACC + 28672;                      // float [64]

// ---------------- helpers ----------------
typedef __attribute__((ext_vector_type(8)))  short  short8;
typedef __attribute__((ext_vector_type(16))) float  floatx16;

__device__ __forceinline__ float bflo(unsigned w){ union{unsigned u;float f;}c; c.u=w<<16; return c.f; }
__device__ __forceinline__ float bfhi(unsigned w){ union{unsigned u;float f;}c; c.u=w&0xffff0000u; return c.f; }
__device__ __forceinline__ float ubf(unsigned short h){ union{unsigned u;float f;}c; c.u=((unsigned)h)<<16; return c.f; }
__device__ __forceinline__ unsigned short f2bf(float x){ __hip_bfloat16 b=__float2bfloat16(x); return *(unsigned short*)&b; }
__device__ __forceinline__ float geluf(float x){ return 0.5f*x*(1.0f+erff(x*0.70710678118654752f)); }
__device__ __forceinline__ float sigmf(float x){ return 1.0f/(1.0f+__expf(-x)); }
__device__ __forceinline__ short8 ld8(const unsigned short* p){
  union{uint4 u; short8 s;}c; c.u=*(const uint4*)p; return c.s;
}
__device__ __forceinline__ floatx16 fzero16(){
  floatx16 x;
  #pragma unroll
  for(int i=0;i<16;i++) x[i]=0.f;
  return x;
}

// Aggregator grid barrier, zero RMW (see round-1 notes).
__device__ __forceinline__ void gridbar2(unsigned* __restrict__ barr, int bid, int t, unsigned ep){
  __syncthreads();
  if (t==0)
    __hip_atomic_store(&barr[bid<<3], ep, __ATOMIC_RELAXED, __HIP_MEMORY_SCOPE_AGENT);
  if (bid==0){
    if (t<64){
      while (__hip_atomic_load(&barr[t<<3], __ATOMIC_RELAXED, __HIP_MEMORY_SCOPE_AGENT) < ep)
        __builtin_amdgcn_s_sleep(1);
    }
    __syncthreads();
    if (t<8)
      __hip_atomic_store(&barr[512+(t<<3)], ep, __ATOMIC_RELAXED, __HIP_MEMORY_SCOPE_AGENT);
  } else if (t==0){
    while (__hip_atomic_load(&barr[512+((bid&7)<<3)], __ATOMIC_RELAXED, __HIP_MEMORY_SCOPE_AGENT) < ep)
      __builtin_amdgcn_s_sleep(1);
  }
  __syncthreads();
}

// ---------------- cnt per atom ----------------
__global__ __launch_bounds__(256) void cnt_kern(const int* __restrict__ cm, float* __restrict__ cntf){
  __shared__ int sd[256];
  const int a=blockIdx.x, t=threadIdx.x;
  int s=0;
  for (int i=t;i<NV;i+=256) s+=cm[a*NV+i];
  sd[t]=s; __syncthreads();
  for (int o=128;o>0;o>>=1){ if(t<o) sd[t]+=sd[t+o]; __syncthreads(); }
  if (t==0) cntf[a]=(float)sd[0];
}

// ---------------- K/V projection -> bf16 hi/lo splits ----------------
// K: row-major [f][128] hi/lo.  V: transposed [d][NFP] hi/lo (for pv B-frags).
__global__ __launch_bounds__(256)
void kvproj_kern(const float* __restrict__ fe,
                 const float* __restrict__ Wk, const float* __restrict__ bk,
                 const float* __restrict__ Wv, const float* __restrict__ bv,
                 unsigned short* __restrict__ Kh, unsigned short* __restrict__ Kl,
                 unsigned short* __restrict__ Vth, unsigned short* __restrict__ Vtl){
  __shared__ float As[32][68];
  __shared__ float Bs[32][132];
  const int t=threadIdx.x;
  const int f0=blockIdx.x*64;
  const float* W  = blockIdx.y ? Wv : Wk;
  const float* bb = blockIdx.y ? bv : bk;
  float acc[4][8];
  #pragma unroll
  for(int i=0;i<4;i++){ for(int j=0;j<8;j++) acc[i][j]=0.f; }
  for (int kc=0;kc<128;kc+=32){
    { const int floc=t>>2, koff=(t&3)*8; const int f=f0+floc;
      if (f<NF){
        const float* src=fe+((size_t)f<<7)+kc+koff;
        float4 a=*(const float4*)src, b=*(const float4*)(src+4);
        As[koff+0][floc]=a.x; As[koff+1][floc]=a.y; As[koff+2][floc]=a.z; As[koff+3][floc]=a.w;
        As[koff+4][floc]=b.x; As[koff+5][floc]=b.y; As[koff+6][floc]=b.z; As[koff+7][floc]=b.w;
      } else { for(int i=0;i<8;i++) As[koff+i][floc]=0.f; } }
    { const int kk=t>>3, coff=(t&7)*16;
      const float* src=W+((size_t)(kc+kk)<<7)+coff;
      float4 a=*(const float4*)src, b=*(const float4*)(src+4), c=*(const float4*)(src+8), d=*(const float4*)(src+12);
      Bs[kk][coff+0]=a.x;Bs[kk][coff+1]=a.y;Bs[kk][coff+2]=a.z;Bs[kk][coff+3]=a.w;
      Bs[kk][coff+4]=b.x;Bs[kk][coff+5]=b.y;Bs[kk][coff+6]=b.z;Bs[kk][coff+7]=b.w;
      Bs[kk][coff+8]=c.x;Bs[kk][coff+9]=c.y;Bs[kk][coff+10]=c.z;Bs[kk][coff+11]=c.w;
      Bs[kk][coff+12]=d.x;Bs[kk][coff+13]=d.y;Bs[kk][coff+14]=d.z;Bs[kk][coff+15]=d.w; }
    __syncthreads();
    const int mloc=(t&15)*4, nloc=(t>>4)*8;
    #pragma unroll
    for (int kk=0;kk<32;kk++){
      const float4 a=*(const float4*)&As[kk][mloc];
      const float4 b0=*(const float4*)&Bs[kk][nloc];
      const float4 b1=*(const float4*)&Bs[kk][nloc+4];
      const float am[4]={a.x,a.y,a.z,a.w};
      const float bn[8]={b0.x,b0.y,b0.z,b0.w,b1.x,b1.y,b1.z,b1.w};
      #pragma unroll
      for(int mi=0;mi<4;mi++){
        #pragma unroll
        for(int ni=0;ni<8;ni++) acc[mi][ni]=fmaf(am[mi],bn[ni],acc[mi][ni]);
      }
    }
    __syncthreads();
  }
  const int mloc=(t&15)*4, nloc=(t>>4)*8;
  if (blockIdx.y==0){
    #pragma unroll
    for(int mi=0;mi<4;mi++){
      const int f=f0+mloc+mi;
      unsigned short hi[8], lo[8];
      #pragma unroll
      for(int ni=0;ni<8;ni++){
        const float o=(f<NF)? (acc[mi][ni]+bb[nloc+ni]) : 0.f;
        hi[ni]=f2bf(o); lo[ni]=f2bf(o-ubf(hi[ni]));
      }
      uint4 ph, pl;
      ph.x=(unsigned)hi[0]|((unsigned)hi[1]<<16); ph.y=(unsigned)hi[2]|((unsigned)hi[3]<<16);
      ph.z=(unsigned)hi[4]|((unsigned)hi[5]<<16); ph.w=(unsigned)hi[6]|((unsigned)hi[7]<<16);
      pl.x=(unsigned)lo[0]|((unsigned)lo[1]<<16); pl.y=(unsigned)lo[2]|((unsigned)lo[3]<<16);
      pl.z=(unsigned)lo[4]|((unsigned)lo[5]<<16); pl.w=(unsigned)lo[6]|((unsigned)lo[7]<<16);
      *(uint4*)(Kh+(size_t)f*128+nloc)=ph;
      *(uint4*)(Kl+(size_t)f*128+nloc)=pl;
    }
  } else {
    #pragma unroll
    for(int ni=0;ni<8;ni++){
      const int d=nloc+ni;
      unsigned short hi[4], lo[4];
      #pragma unroll
      for(int mi=0;mi<4;mi++){
        const int f=f0+mloc+mi;
        const float o=(f<NF)? (acc[mi][ni]+bb[d]) : 0.f;
        hi[mi]=f2bf(o); lo[mi]=f2bf(o-ubf(hi[mi]));
      }
      *(uint2*)(Vth+(size_t)d*NFP+f0+mloc)=make_uint2((unsigned)hi[0]|((unsigned)hi[1]<<16),(unsigned)hi[2]|((unsigned)hi[3]<<16));
      *(uint2*)(Vtl+(size_t)d*NFP+f0+mloc)=make_uint2((unsigned)lo[0]|((unsigned)lo[1]<<16),(unsigned)lo[2]|((unsigned)lo[3]<<16));
    }
  }
}

// ---------------- q = h @ Wq + bq -> bf16 hi/lo ----------------
__global__ __launch_bounds__(128)
void qproj_kern(const float* __restrict__ h, const float* __restrict__ Wq,
                const float* __restrict__ bq,
                unsigned short* __restrict__ qh, unsigned short* __restrict__ ql){
  __shared__ float hs[128];
  const int v=blockIdx.x, c=threadIdx.x;
  hs[c]=h[(v<<7)+c];
  __syncthreads();
  float acc=bq[c];
  #pragma unroll 8
  for (int k=0;k<128;k++) acc=fmaf(hs[k],Wq[(k<<7)+c],acc);
  const unsigned short hi=f2bf(acc);
  qh[(v<<7)+c]=hi; ql[(v<<7)+c]=f2bf(acc-ubf(hi));
}

// ---------------- MFMA scores (main loop): P = bf16(exp(scale*q.K^T)) ----------------
// 32x32x16 bf16 MFMA, hi/lo split (3 products) for near-fp32 scores.
// Grid (98, 16): block = 64 v-rows x 512 f-cols; wave w loops 4 f-subtiles of 32.
__global__ __launch_bounds__(256)
void scoresM_kern(const unsigned short* __restrict__ qh, const unsigned short* __restrict__ ql,
                  const unsigned short* __restrict__ Kh, const unsigned short* __restrict__ Kl,
                  unsigned short* __restrict__ Pb){
  const int t=threadIdx.x, w=t>>6, lane=t&63;
  const int v0=blockIdx.y*64;
  const int col=lane&31, kg=lane>>5;
  const int r0=v0+col;
  const size_t a0base=(size_t)r0*128, a1base=(size_t)(r0+32)*128;
  for (int ft=0; ft<4; ft++){
    const int fsub=blockIdx.x*512+(w+4*ft)*32;
    if (fsub>=NFP) break;
    const int f=fsub+col;
    const size_t bbase=(size_t)f*128;
    floatx16 acc0=fzero16(), acc1=fzero16();
    #pragma unroll
    for (int ks=0; ks<8; ks++){
      const int ko=ks*16+kg*8;
      short8 a0h=ld8(qh+a0base+ko), a0l=ld8(ql+a0base+ko);
      short8 a1h=ld8(qh+a1base+ko), a1l=ld8(ql+a1base+ko);
      short8 bh =ld8(Kh+bbase+ko),  bl =ld8(Kl+bbase+ko);
      acc0=__builtin_amdgcn_mfma_f32_32x32x16_bf16(a0h,bh,acc0,0,0,0);
      acc0=__builtin_amdgcn_mfma_f32_32x32x16_bf16(a0h,bl,acc0,0,0,0);
      acc0=__builtin_amdgcn_mfma_f32_32x32x16_bf16(a0l,bh,acc0,0,0,0);
      acc1=__builtin_amdgcn_mfma_f32_32x32x16_bf16(a1h,bh,acc1,0,0,0);
      acc1=__builtin_amdgcn_mfma_f32_32x32x16_bf16(a1h,bl,acc1,0,0,0);
      acc1=__builtin_amdgcn_mfma_f32_32x32x16_bf16(a1l,bh,acc1,0,0,0);
    }
    const bool inF=(f<NF);
    #pragma unroll
    for (int r=0;r<16;r++){
      const int rr=(r&3)+8*(r>>2)+4*kg;
      {
        const int row=v0+rr;
        const float s=acc0[r]*SCALE_QK;
        const float ep=inF? __expf(s):0.f;
        Pb[(size_t)row*NFP+f]=f2bf(ep);
      }
      {
        const int row=v0+32+rr;
        const float s=acc1[r]*SCALE_QK;
        const float ep=inF? __expf(s):0.f;
        Pb[(size_t)row*NFP+f]=f2bf(ep);
      }
    }
  }
}

// ---------------- MFMA PV: part[slice] = P_slice @ V_slice  (+ Z row-sums via ones-MFMA) ----
// Grid (25, 16): block = 64 v-rows x 128 d; wave w owns d-cols [32w,32w+32).
template<int SUMZ>
__global__ __launch_bounds__(256)
void pvM_kern(const unsigned short* __restrict__ Pb,
              const unsigned short* __restrict__ Vth, const unsigned short* __restrict__ Vtl,
              float* __restrict__ part, float* __restrict__ accg){
  __shared__ float Zs[64];
  const int t=threadIdx.x, w=t>>6, lane=t&63;
  const int slice=blockIdx.x, v0=blockIdx.y*64;
  const int col=lane&31, kg=lane>>5;
  const int d0=w*32;
  const int fbeg=slice*2048, fend=min(fbeg+2048,(int)NFP);
  if (SUMZ){ if (t<64) Zs[t]=0.f; __syncthreads(); }
  floatx16 acc0=fzero16(), acc1=fzero16(), z0=fzero16(), z1=fzero16();
  const short8 ones={(short)0x3F80,(short)0x3F80,(short)0x3F80,(short)0x3F80,
                     (short)0x3F80,(short)0x3F80,(short)0x3F80,(short)0x3F80};
  const unsigned short* pr0=Pb+(size_t)(v0+col)*NFP;
  const unsigned short* pr1=Pb+(size_t)(v0+32+col)*NFP;
  const unsigned short* vh =Vth+(size_t)(d0+col)*NFP;
  const unsigned short* vl =Vtl+(size_t)(d0+col)*NFP;
  for (int fc=fbeg; fc<fend; fc+=16){
    const int ko=fc+kg*8;
    short8 a0=ld8(pr0+ko), a1=ld8(pr1+ko);
    short8 bh=ld8(vh+ko),  bl=ld8(vl+ko);
    acc0=__builtin_amdgcn_mfma_f32_32x32x16_bf16(a0,bh,acc0,0,0,0);
    acc0=__builtin_amdgcn_mfma_f32_32x32x16_bf16(a0,bl,acc0,0,0,0);
    acc1=__builtin_amdgcn_mfma_f32_32x32x16_bf16(a1,bh,acc1,0,0,0);
    acc1=__builtin_amdgcn_mfma_f32_32x32x16_bf16(a1,bl,acc1,0,0,0);
    if (SUMZ && (((fc>>4)&3)==w)){
      z0=__builtin_amdgcn_mfma_f32_32x32x16_bf16(a0,ones,z0,0,0,0);
      z1=__builtin_amdgcn_mfma_f32_32x32x16_bf16(a1,ones,z1,0,0,0);
    }
  }
  const int d=d0+col;
  #pragma unroll
  for (int r=0;r<16;r++){
    const int rr=(r&3)+8*(r>>2)+4*kg;
    part[(((size_t)slice*NV+(v0+rr))<<7)+d]   =acc0[r];
    part[(((size_t)slice*NV+(v0+32+rr))<<7)+d]=acc1[r];
  }
  if (SUMZ){
    if (col==0){
      #pragma unroll
      for (int r=0;r<16;r++){
        const int rr=(r&3)+8*(r>>2)+4*kg;
        atomicAdd(&Zs[rr],z0[r]);
        atomicAdd(&Zs[32+rr],z1[r]);
      }
    }
    __syncthreads();
    if (t<64) atomicAdd(&accg[v0+t],Zs[t]);
  }
}

// ---------------- FINAL scores (SIMD fp32, runs once): gumbel + 4 sums ----------------
__global__ __launch_bounds__(256)
void scoresF_kern(const unsigned short* __restrict__ qh, const unsigned short* __restrict__ ql,
                  const unsigned short* __restrict__ Kh, const unsigned short* __restrict__ Kl,
                  const float* __restrict__ gum, unsigned short* __restrict__ Pb,
                  float* __restrict__ accg){
  __shared__ float As[32][68];
  __shared__ float Bs[32][132];
  __shared__ float Zs[64], Zls[64], Yps[64], Yls[64];
  const int t=threadIdx.x;
  const int f0=blockIdx.x*128;
  const int v0=blockIdx.y*64;
  float acc[4][8];
  #pragma unroll
  for(int i=0;i<4;i++){ for(int j=0;j<8;j++) acc[i][j]=0.f; }
  if (t<64){ Zs[t]=0.f; Zls[t]=0.f; Yps[t]=0.f; Yls[t]=0.f; }
  for (int kc=0;kc<128;kc+=32){
    { const int vloc=t>>2, koff=(t&3)*8;
      const size_t base=((size_t)(v0+vloc)<<7)+kc+koff;
      uint4 H=*(const uint4*)(qh+base), L=*(const uint4*)(ql+base);
      As[koff+0][vloc]=bflo(H.x)+bflo(L.x); As[koff+1][vloc]=bfhi(H.x)+bfhi(L.x);
      As[koff+2][vloc]=bflo(H.y)+bflo(L.y); As[koff+3][vloc]=bfhi(H.y)+bfhi(L.y);
      As[koff+4][vloc]=bflo(H.z)+bflo(L.z); As[koff+5][vloc]=bfhi(H.z)+bfhi(L.z);
      As[koff+6][vloc]=bflo(H.w)+bflo(L.w); As[koff+7][vloc]=bfhi(H.w)+bfhi(L.w); }
    { const int floc=t>>1, koff=(t&1)*16; const int f=f0+floc;
      const size_t base=((size_t)f<<7)+kc+koff;
      uint4 H0=*(const uint4*)(Kh+base), H1=*(const uint4*)(Kh+base+8);
      uint4 L0=*(const uint4*)(Kl+base), L1=*(const uint4*)(Kl+base+8);
      Bs[koff+0][floc]=bflo(H0.x)+bflo(L0.x); Bs[koff+1][floc]=bfhi(H0.x)+bfhi(L0.x);
      Bs[koff+2][floc]=bflo(H0.y)+bflo(L0.y); Bs[koff+3][floc]=bfhi(H0.y)+bfhi(L0.y);
      Bs[koff+4][floc]=bflo(H0.z)+bflo(L0.z); Bs[koff+5][floc]=bfhi(H0.z)+bfhi(L0.z);
      Bs[koff+6][floc]=bflo(H0.w)+bflo(L0.w); Bs[koff+7][floc]=bfhi(H0.w)+bfhi(L0.w);
      Bs[koff+8][floc]=bflo(H1.x)+bflo(L1.x); Bs[koff+9][floc]=bfhi(H1.x)+bfhi(L1.x);
      Bs[koff+10][floc]=bflo(H1.y)+bflo(L1.y); Bs[koff+11][floc]=bfhi(H1.y)+bfhi(L1.y);
      Bs[koff+12][floc]=bflo(H1.z)+bflo(L1.z); Bs[koff+13][floc]=bfhi(H1.z)+bfhi(L1.z);
      Bs[koff+14][floc]=bflo(H1.w)+bflo(L1.w); Bs[koff+15][floc]=bfhi(H1.w)+bfhi(L1.w); }
    __syncthreads();
    const int mloc=(t&15)*4, nloc=(t>>4)*8;
    #pragma unroll
    for (int kk=0;kk<32;kk++){
      const float4 a=*(const float4*)&As[kk][mloc];
      const float4 b0=*(const float4*)&Bs[kk][nloc];
      const float4 b1=*(const float4*)&Bs[kk][nloc+4];
      const float am[4]={a.x,a.y,a.z,a.w};
      const float bn[8]={b0.x,b0.y,b0.z,b0.w,b1.x,b1.y,b1.z,b1.w};
      #pragma unroll
      for(int mi=0;mi<4;mi++){
        #pragma unroll
        for(int ni=0;ni<8;ni++) acc[mi][ni]=fmaf(am[mi],bn[ni],acc[mi][ni]);
      }
    }
    __syncthreads();
  }
  const int mloc=(t&15)*4, nloc=(t>>4)*8;
  #pragma unroll
  for(int mi=0;mi<4;mi++){
    const int v=v0+mloc+mi;
    float zp=0.f, zl=0.f, yp=0.f, yl=0.f;
    float uu[8];
    { const int fbase=f0+nloc;
      if (fbase+8<=NF){
        const float* gsrc=gum+(size_t)v*NF+fbase;
        float4 g0=*(const float4*)gsrc, g1=*(const float4*)(gsrc+4);
        uu[0]=g0.x;uu[1]=g0.y;uu[2]=g0.z;uu[3]=g0.w;uu[4]=g1.x;uu[5]=g1.y;uu[6]=g1.z;uu[7]=g1.w;
      } else {
        for(int i=0;i<8;i++){ int f=fbase+i; uu[i]=(f<NF)? gum[(size_t)v*NF+f] : 0.5f; }
      } }
    unsigned short pr[8];
    #pragma unroll
    for(int ni=0;ni<8;ni++){
      const int f=f0+nloc+ni;
      const float s=acc[mi][ni]*SCALE_QK;
      float pv_=0.f;
      if (f<NF){
        const float ep=__expf(s);
        const float g=-__logf(-__logf(uu[ni]));
        const float el=__expf(2.0f*(s+g));
        pv_=el; zl+=el; yl+=el*s; zp+=ep; yp+=ep*s;
      }
      pr[ni]=f2bf(pv_);
    }
    uint4 pk;
    pk.x=(unsigned)pr[0]|((unsigned)pr[1]<<16);
    pk.y=(unsigned)pr[2]|((unsigned)pr[3]<<16);
    pk.z=(unsigned)pr[4]|((unsigned)pr[5]<<16);
    pk.w=(unsigned)pr[6]|((unsigned)pr[7]<<16);
    *(uint4*)(Pb+(size_t)v*NFP+f0+nloc)=pk;
    atomicAdd(&Zs[mloc+mi],zp);
    atomicAdd(&Zls[mloc+mi],zl); atomicAdd(&Yps[mloc+mi],yp); atomicAdd(&Yls[mloc+mi],yl);
  }
  __syncthreads();
  if (t<64){
    atomicAdd(&accg[v0+t],Zs[t]);
    atomicAdd(&accg[1024+v0+t],Zls[t]);
    atomicAdd(&accg[2048+v0+t],Yps[t]);
    atomicAdd(&accg[3072+v0+t],Yls[t]);
  }
}

// ---------------- main-loop gate update ----------------
__global__ __launch_bounds__(256)
void gate_kern(float* __restrict__ h, const float* __restrict__ part, const float* __restrict__ Z,
               const float* __restrict__ Wm1, const float* __restrict__ bm1,
               const float* __restrict__ Wm2, const float* __restrict__ bm2){
  const int t=threadIdx.x, w=t>>6, lane=t&63;
  const int v=(blockIdx.x<<2)+w;
  const float h0=h[(v<<7)+lane], h1=h[(v<<7)+64+lane];
  const float zr=1.0f/Z[v];
  float c0=0.f,c1=0.f;
  for (int s=0;s<NSLICE;s++){
    c0+=part[(((size_t)s*NV+v)<<7)+lane];
    c1+=part[(((size_t)s*NV+v)<<7)+64+lane];
  }
  c0*=zr; c1*=zr;
  float y0=bm1[lane], y1=bm1[64+lane];
  for (int k=0;k<64;k++){ const float a=__shfl(h0,k); y0=fmaf(a,Wm1[(k<<7)+lane],y0);      y1=fmaf(a,Wm1[(k<<7)+64+lane],y1); }
  for (int k=0;k<64;k++){ const float a=__shfl(h1,k); y0=fmaf(a,Wm1[((64+k)<<7)+lane],y0); y1=fmaf(a,Wm1[((64+k)<<7)+64+lane],y1); }
  for (int k=0;k<64;k++){ const float a=__shfl(c0,k); y0=fmaf(a,Wm1[((128+k)<<7)+lane],y0);y1=fmaf(a,Wm1[((128+k)<<7)+64+lane],y1); }
  for (int k=0;k<64;k++){ const float a=__shfl(c1,k); y0=fmaf(a,Wm1[((192+k)<<7)+lane],y0);y1=fmaf(a,Wm1[((192+k)<<7)+64+lane],y1); }
  y0=geluf(y0); y1=geluf(y1);
  float z0=bm2[lane], z1=bm2[64+lane];
  for (int k=0;k<64;k++){ const float a=__shfl(y0,k); z0=fmaf(a,Wm2[(k<<7)+lane],z0);      z1=fmaf(a,Wm2[(k<<7)+64+lane],z1); }
  for (int k=0;k<64;k++){ const float a=__shfl(y1,k); z0=fmaf(a,Wm2[((64+k)<<7)+lane],z0); z1=fmaf(a,Wm2[((64+k)<<7)+64+lane],z1); }
  const float g0=sigmf(z0), g1=sigmf(z1);
  h[(v<<7)+lane]   = fmaf(g0,c0-h0,h0);
  h[(v<<7)+64+lane]= fmaf(g1,c1-h1,h1);
}

// ---------------- cooc scan (persistent, 64 blocks x 1024 thr) ----------------
__global__ __launch_bounds__(1024,4)
void cooc_kern(float* __restrict__ h, const int* __restrict__ cm, const float* __restrict__ cntf,
               const float* __restrict__ Wc1, const float* __restrict__ bc1,
               const float* __restrict__ Wc2, const float* __restrict__ bc2,
               float* __restrict__ bufs, unsigned* __restrict__ barr){
  __shared__ unsigned W1s[128*64];
  __shared__ unsigned W2s[104*64];
  __shared__ float ypart[1024];
  __shared__ float avgs[128];
  __shared__ float yavs[128];
  __shared__ float seedb[128];
  __shared__ float cnts[64];
  __shared__ int   anyf;
  const int t=threadIdx.x, w=t>>6, lane=t&63;
  const int bid=blockIdx.x;
  const int v=(bid<<4)+w;
  const int stripe=bid&7;
  for (int i=t;i<128*64;i+=1024){ const int k=i>>6,l=i&63;
    W1s[i]=(unsigned)f2bf(Wc1[(k<<7)+l])|(((unsigned)f2bf(Wc1[(k<<7)+64+l]))<<16); }
  for (int i=t;i<104*64;i+=1024){ const int k=i>>6,l=i&63;
    W2s[i]=(unsigned)f2bf(Wc2[(k<<7)+l])|(((unsigned)f2bf(Wc2[(k<<7)+64+l]))<<16); }
  if (t<64) cnts[t]=cntf[t];
  const unsigned long long amask=__ballot(cm[lane*NV+v]!=0);
  float h0=h[(v<<7)+lane], h1=h[(v<<7)+64+lane];
  const float b10=bc1[lane], b11=bc1[64+lane];
  const float b20=bc2[lane], b21=bc2[64+lane];
  if (t<128) seedb[t]=0.f;
  if (t==0) anyf=0;
  __syncthreads();
  if (amask&1ull){ atomicAdd(&seedb[lane],h0); atomicAdd(&seedb[64+lane],h1); if(lane==0) anyf=1; }
  __syncthreads();
  if (anyf && t<128) atomicAdd(&bufs[(stripe<<7)+t],seedb[t]);
  unsigned ep=0;
  gridbar2(barr,bid,t,++ep);
  for (int a=0;a<NA;a++){
    const int cur=a%3, nxt=(a+1)%3, zz=(a+2)%3;
    const float cf=cnts[a];
    if (t<128){
      float s=0.f;
      #pragma unroll
      for (int sp=0;sp<8;sp++)
        s+=__hip_atomic_load(&bufs[(cur<<10)+(sp<<7)+t],__ATOMIC_RELAXED,__HIP_MEMORY_SCOPE_AGENT);
      avgs[t]=s/fmaxf(cf,1.0f);
    }
    if (bid==0)
      __hip_atomic_store(&bufs[(zz<<10)+t],0.0f,__ATOMIC_RELAXED,__HIP_MEMORY_SCOPE_AGENT);
    __syncthreads();
    { const int seg=t>>7, ok=t&127;
      const int kb=seg<<4;
      float s=0.f;
      #pragma unroll
      for (int j=0;j<16;j++) s=fmaf(avgs[kb+j],Wc1[((128+kb+j)<<7)+ok],s);
      ypart[(seg<<7)+ok]=s; }
    __syncthreads();
    if (t<128){
      float s=0.f;
      #pragma unroll
      for (int seg=0;seg<8;seg++) s+=ypart[(seg<<7)+t];
      yavs[t]=s;
    } else if (t<256) seedb[t-128]=0.f;
    else if (t==256) anyf=0;
    __syncthreads();
    const bool act=((amask>>a)&1ull)&&(cf>=2.0f);
    if (act){
      const float av0=avgs[lane], av1=avgs[64+lane];
      float y0=b10+yavs[lane], y1=b11+yavs[64+lane];
      #pragma unroll 8
      for (int k=0;k<64;k++){ const float hk=__shfl(h0,k); const unsigned wp=W1s[(k<<6)+lane];
        y0=fmaf(hk,bflo(wp),y0); y1=fmaf(hk,bfhi(wp),y1); }
      #pragma unroll 8
      for (int k=0;k<64;k++){ const float hk=__shfl(h1,k); const unsigned wp=W1s[((64+k)<<6)+lane];
        y0=fmaf(hk,bflo(wp),y0); y1=fmaf(hk,bfhi(wp),y1); }
      y0=geluf(y0); y1=geluf(y1);
      float z0=b20, z1=b21;
      #pragma unroll 8
      for (int k=0;k<64;k++){ const float yk=__shfl(y0,k); const unsigned wp=W2s[(k<<6)+lane];
        z0=fmaf(yk,bflo(wp),z0); z1=fmaf(yk,bfhi(wp),z1); }
      #pragma unroll 8
      for (int k=0;k<40;k++){ const float yk=__shfl(y1,k); const unsigned wp=W2s[((64+k)<<6)+lane];
        z0=fmaf(yk,bflo(wp),z0); z1=fmaf(yk,bfhi(wp),z1); }
      for (int k=40;k<64;k++){ const float yk=__shfl(y1,k);
        z0=fmaf(yk,Wc2[((64+k)<<7)+lane],z0); z1=fmaf(yk,Wc2[((64+k)<<7)+64+lane],z1); }
      const float g0=sigmf(z0), g1=sigmf(z1);
      h0=fmaf(g0,av0-h0,h0); h1=fmaf(g1,av1-h1,h1);
    }
    if (a<NA-1){
      if ((amask>>(a+1))&1ull){
        atomicAdd(&seedb[lane],h0); atomicAdd(&seedb[64+lane],h1);
        if (lane==0) anyf=1;
      }
      __syncthreads();
      if (anyf && t<128)
        atomicAdd(&bufs[(nxt<<10)+(stripe<<7)+t],seedb[t]);
      gridbar2(barr,bid,t,++ep);
    }
  }
  h[(v<<7)+lane]=h0; h[(v<<7)+64+lane]=h1;
}

// ---------------- final write-out ----------------
__global__ __launch_bounds__(256)
void writeout_kern(const float* __restrict__ accg, const float* __restrict__ part,
                   float* __restrict__ out){
  const int b=blockIdx.x, t=threadIdx.x;
  const int v0=b*16;
  for (int i=t;i<16*128;i+=256){
    const int v=v0+(i>>7), d=i&127;
    float s=0.f;
    for (int sl=0;sl<NSLICE;sl++) s+=part[(((size_t)sl*NV+v)<<7)+d];
    out[1+((size_t)v<<7)+d]=s/accg[1024+v];
  }
  __shared__ float es[16], hsv[16];
  if (t<16){
    const int v=v0+t;
    const float Zp=accg[v], Zl=accg[1024+v], Yp=accg[2048+v], Yl=accg[3072+v];
    es[t]=-Yl/Zl;
    hsv[t]=-(Yp/Zp-logf(Zp));
  }
  __syncthreads();
  if (t==0){
    float a=0.f,c=0.f;
    for(int i=0;i<16;i++){ a+=es[i]; c+=hsv[i]; }
    atomicAdd(&out[0],a);
    atomicAdd(&out[1+(size_t)NV*128],c);
  }
}

// ---------------- host ----------------
extern "C" void kernel_launch(void* const* d_in, const int* in_sizes, int n_in,
                              void* d_out, int out_size, void* d_ws, size_t ws_size,
                              hipStream_t stream){
  (void)in_sizes; (void)n_in; (void)ws_size;
  const float* fe =(const float*)d_in[0];
  const float* vi =(const float*)d_in[1];
  const int*   cm =(const int*)  d_in[2];
  const float* gum=(const float*)d_in[3];
  const float* Wq =(const float*)d_in[4];  const float* bq =(const float*)d_in[5];
  const float* Wk =(const float*)d_in[6];  const float* bk =(const float*)d_in[7];
  const float* Wv =(const float*)d_in[8];  const float* bv =(const float*)d_in[9];
  const float* Wm1=(const float*)d_in[10]; const float* bm1=(const float*)d_in[11];
  const float* Wm2=(const float*)d_in[12]; const float* bm2=(const float*)d_in[13];
  const float* Wc1=(const float*)d_in[14]; const float* bc1=(const float*)d_in[15];
  const float* Wc2=(const float*)d_in[16]; const float* bc2=(const float*)d_in[17];
  float* out=(float*)d_out;
  char* w8=(char*)d_ws;
  unsigned short* Kh =(unsigned short*)(w8+OFF_KH);
  unsigned short* Kl =(unsigned short*)(w8+OFF_KL);
  unsigned short* Vth=(unsigned short*)(w8+OFF_VTH);
  unsigned short* Vtl=(unsigned short*)(w8+OFF_VTL);
  unsigned short* Pb =(unsigned short*)(w8+OFF_P);
  float* hb  =(float*)(w8+OFF_H);
  unsigned short* qhb=(unsigned short*)(w8+OFF_QH);
  unsigned short* qlb=(unsigned short*)(w8+OFF_QL);
  float* part=(float*)(w8+OFF_PART);
  float* accb=(float*)(w8+OFF_ACC);
  float* avgb=accb+4096;
  float* cntf=(float*)(w8+OFF_CNT);
  unsigned* barr=(unsigned*)(w8+OFF_P);   // overlays dead-at-cooc-time P head

  hipMemsetAsync(out,0,(size_t)out_size*4,stream);
  hipMemcpyAsync(hb,vi,(size_t)NV*128*4,hipMemcpyDeviceToDevice,stream);
  cnt_kern<<<NA,256,0,stream>>>(cm,cntf);
  kvproj_kern<<<dim3(NFP/64,2),256,0,stream>>>(fe,Wk,bk,Wv,bv,Kh,Kl,Vth,Vtl);

  for (int it=0; it<3; it++){
    hipMemsetAsync(accb,0,28672,stream);
    qproj_kern<<<NV,128,0,stream>>>(hb,Wq,bq,qhb,qlb);
    scoresM_kern<<<dim3(98,16),256,0,stream>>>(qhb,qlb,Kh,Kl,Pb);
    pvM_kern<1><<<dim3(NSLICE,16),256,0,stream>>>(Pb,Vth,Vtl,part,accb);
    gate_kern<<<NV/4,256,0,stream>>>(hb,part,accb,Wm1,bm1,Wm2,bm2);
    hipMemsetAsync(barr,0,2304,stream);
    cooc_kern<<<64,1024,0,stream>>>(hb,cm,cntf,Wc1,bc1,Wc2,bc2,avgb,barr);
  }

  hipMemsetAsync(accb,0,28672,stream);
  qproj_kern<<<NV,128,0,stream>>>(hb,Wq,bq,qhb,qlb);
  scoresF_kern<<<dim3(NFP/128,16),256,0,stream>>>(qhb,qlb,Kh,Kl,gum,Pb,accb);
  pvM_kern<0><<<dim3(NSLICE,16),256,0,stream>>>(Pb,Vth,Vtl,part,accb);
  writeout_kern<<<64,256,0,stream>>>(accb,part,out);
}

// Round 4
// 4346.454 us; speedup vs baseline: 1.4319x; 1.2833x over previous
//
#include <hip/hip_runtime.h>
#include <hip/hip_bf16.h>
#include <math.h>

#define NF 50000
#define NFP 50048
#define NV 1024
#define NA 64
#define NSLICE 25
#define SCALE_QK 0.088388347648318447f

// ---------------- ws layout (bytes) ----------------
static const size_t OFF_KH   = 0;                                    // ushort [NFP*128]
static const size_t OFF_KL   = OFF_KH  + (size_t)NFP*128*2;          // ushort [NFP*128]
static const size_t OFF_VTH  = OFF_KL  + (size_t)NFP*128*2;          // ushort [128*NFP] (transposed)
static const size_t OFF_VTL  = OFF_VTH + (size_t)128*NFP*2;          // ushort [128*NFP]
static const size_t OFF_P    = OFF_VTL + (size_t)128*NFP*2;          // bf16  [NV*NFP]
static const size_t OFF_H    = OFF_P   + (size_t)NV*NFP*2;           // float [NV*128]
static const size_t OFF_QH   = OFF_H   + (size_t)NV*128*4;           // ushort[NV*128]
static const size_t OFF_QL   = OFF_QH  + (size_t)NV*128*2;           // ushort[NV*128]
static const size_t OFF_PART = OFF_QL  + (size_t)NV*128*2;           // float [25*NV*128]
static const size_t OFF_ACC  = OFF_PART+ (size_t)NSLICE*NV*128*4;    // float Z,Zl,Yp,Yl [4*1024] + avg[3*1024]
static const size_t OFF_CNT  = OFF_ACC + 28672;                      // float [64]

// ---------------- helpers ----------------
typedef __attribute__((ext_vector_type(8)))  short  short8;
typedef __attribute__((ext_vector_type(16))) float  floatx16;
#define MFMA32 __builtin_amdgcn_mfma_f32_32x32x16_bf16

__device__ __forceinline__ float bflo(unsigned w){ union{unsigned u;float f;}c; c.u=w<<16; return c.f; }
__device__ __forceinline__ float bfhi(unsigned w){ union{unsigned u;float f;}c; c.u=w&0xffff0000u; return c.f; }
__device__ __forceinline__ float ubf(unsigned short h){ union{unsigned u;float f;}c; c.u=((unsigned)h)<<16; return c.f; }
__device__ __forceinline__ unsigned short f2bf(float x){ __hip_bfloat16 b=__float2bfloat16(x); return *(unsigned short*)&b; }
__device__ __forceinline__ float geluf(float x){ return 0.5f*x*(1.0f+erff(x*0.70710678118654752f)); }
__device__ __forceinline__ float sigmf(float x){ return 1.0f/(1.0f+__expf(-x)); }
__device__ __forceinline__ short8 ld8(const unsigned short* p){
  union{uint4 u; short8 s;}c; c.u=*(const uint4*)p; return c.s;
}
__device__ __forceinline__ floatx16 fzero16(){
  floatx16 x;
  #pragma unroll
  for(int i=0;i<16;i++) x[i]=0.f;
  return x;
}

// Aggregator grid barrier, zero RMW (see round-1 notes).
__device__ __forceinline__ void gridbar2(unsigned* __restrict__ barr, int bid, int t, unsigned ep){
  __syncthreads();
  if (t==0)
    __hip_atomic_store(&barr[bid<<3], ep, __ATOMIC_RELAXED, __HIP_MEMORY_SCOPE_AGENT);
  if (bid==0){
    if (t<64){
      while (__hip_atomic_load(&barr[t<<3], __ATOMIC_RELAXED, __HIP_MEMORY_SCOPE_AGENT) < ep)
        __builtin_amdgcn_s_sleep(1);
    }
    __syncthreads();
    if (t<8)
      __hip_atomic_store(&barr[512+(t<<3)], ep, __ATOMIC_RELAXED, __HIP_MEMORY_SCOPE_AGENT);
  } else if (t==0){
    while (__hip_atomic_load(&barr[512+((bid&7)<<3)], __ATOMIC_RELAXED, __HIP_MEMORY_SCOPE_AGENT) < ep)
      __builtin_amdgcn_s_sleep(1);
  }
  __syncthreads();
}

// ---------------- cnt per atom ----------------
__global__ __launch_bounds__(256) void cnt_kern(const int* __restrict__ cm, float* __restrict__ cntf){
  __shared__ int sd[256];
  const int a=blockIdx.x, t=threadIdx.x;
  int s=0;
  for (int i=t;i<NV;i+=256) s+=cm[a*NV+i];
  sd[t]=s; __syncthreads();
  for (int o=128;o>0;o>>=1){ if(t<o) sd[t]+=sd[t+o]; __syncthreads(); }
  if (t==0) cntf[a]=(float)sd[0];
}

// ---------------- K/V projection -> bf16 hi/lo splits ----------------
__global__ __launch_bounds__(256)
void kvproj_kern(const float* __restrict__ fe,
                 const float* __restrict__ Wk, const float* __restrict__ bk,
                 const float* __restrict__ Wv, const float* __restrict__ bv,
                 unsigned short* __restrict__ Kh, unsigned short* __restrict__ Kl,
                 unsigned short* __restrict__ Vth, unsigned short* __restrict__ Vtl){
  __shared__ float As[32][68];
  __shared__ float Bs[32][132];
  const int t=threadIdx.x;
  const int f0=blockIdx.x*64;
  const float* W  = blockIdx.y ? Wv : Wk;
  const float* bb = blockIdx.y ? bv : bk;
  float acc[4][8];
  #pragma unroll
  for(int i=0;i<4;i++){ for(int j=0;j<8;j++) acc[i][j]=0.f; }
  for (int kc=0;kc<128;kc+=32){
    { const int floc=t>>2, koff=(t&3)*8; const int f=f0+floc;
      if (f<NF){
        const float* src=fe+((size_t)f<<7)+kc+koff;
        float4 a=*(const float4*)src, b=*(const float4*)(src+4);
        As[koff+0][floc]=a.x; As[koff+1][floc]=a.y; As[koff+2][floc]=a.z; As[koff+3][floc]=a.w;
        As[koff+4][floc]=b.x; As[koff+5][floc]=b.y; As[koff+6][floc]=b.z; As[koff+7][floc]=b.w;
      } else { for(int i=0;i<8;i++) As[koff+i][floc]=0.f; } }
    { const int kk=t>>3, coff=(t&7)*16;
      const float* src=W+((size_t)(kc+kk)<<7)+coff;
      float4 a=*(const float4*)src, b=*(const float4*)(src+4), c=*(const float4*)(src+8), d=*(const float4*)(src+12);
      Bs[kk][coff+0]=a.x;Bs[kk][coff+1]=a.y;Bs[kk][coff+2]=a.z;Bs[kk][coff+3]=a.w;
      Bs[kk][coff+4]=b.x;Bs[kk][coff+5]=b.y;Bs[kk][coff+6]=b.z;Bs[kk][coff+7]=b.w;
      Bs[kk][coff+8]=c.x;Bs[kk][coff+9]=c.y;Bs[kk][coff+10]=c.z;Bs[kk][coff+11]=c.w;
      Bs[kk][coff+12]=d.x;Bs[kk][coff+13]=d.y;Bs[kk][coff+14]=d.z;Bs[kk][coff+15]=d.w; }
    __syncthreads();
    const int mloc=(t&15)*4, nloc=(t>>4)*8;
    #pragma unroll
    for (int kk=0;kk<32;kk++){
      const float4 a=*(const float4*)&As[kk][mloc];
      const float4 b0=*(const float4*)&Bs[kk][nloc];
      const float4 b1=*(const float4*)&Bs[kk][nloc+4];
      const float am[4]={a.x,a.y,a.z,a.w};
      const float bn[8]={b0.x,b0.y,b0.z,b0.w,b1.x,b1.y,b1.z,b1.w};
      #pragma unroll
      for(int mi=0;mi<4;mi++){
        #pragma unroll
        for(int ni=0;ni<8;ni++) acc[mi][ni]=fmaf(am[mi],bn[ni],acc[mi][ni]);
      }
    }
    __syncthreads();
  }
  const int mloc=(t&15)*4, nloc=(t>>4)*8;
  if (blockIdx.y==0){
    #pragma unroll
    for(int mi=0;mi<4;mi++){
      const int f=f0+mloc+mi;
      unsigned short hi[8], lo[8];
      #pragma unroll
      for(int ni=0;ni<8;ni++){
        const float o=(f<NF)? (acc[mi][ni]+bb[nloc+ni]) : 0.f;
        hi[ni]=f2bf(o); lo[ni]=f2bf(o-ubf(hi[ni]));
      }
      uint4 ph, pl;
      ph.x=(unsigned)hi[0]|((unsigned)hi[1]<<16); ph.y=(unsigned)hi[2]|((unsigned)hi[3]<<16);
      ph.z=(unsigned)hi[4]|((unsigned)hi[5]<<16); ph.w=(unsigned)hi[6]|((unsigned)hi[7]<<16);
      pl.x=(unsigned)lo[0]|((unsigned)lo[1]<<16); pl.y=(unsigned)lo[2]|((unsigned)lo[3]<<16);
      pl.z=(unsigned)lo[4]|((unsigned)lo[5]<<16); pl.w=(unsigned)lo[6]|((unsigned)lo[7]<<16);
      *(uint4*)(Kh+(size_t)f*128+nloc)=ph;
      *(uint4*)(Kl+(size_t)f*128+nloc)=pl;
    }
  } else {
    #pragma unroll
    for(int ni=0;ni<8;ni++){
      const int d=nloc+ni;
      unsigned short hi[4], lo[4];
      #pragma unroll
      for(int mi=0;mi<4;mi++){
        const int f=f0+mloc+mi;
        const float o=(f<NF)? (acc[mi][ni]+bb[d]) : 0.f;
        hi[mi]=f2bf(o); lo[mi]=f2bf(o-ubf(hi[mi]));
      }
      *(uint2*)(Vth+(size_t)d*NFP+f0+mloc)=make_uint2((unsigned)hi[0]|((unsigned)hi[1]<<16),(unsigned)hi[2]|((unsigned)hi[3]<<16));
      *(uint2*)(Vtl+(size_t)d*NFP+f0+mloc)=make_uint2((unsigned)lo[0]|((unsigned)lo[1]<<16),(unsigned)lo[2]|((unsigned)lo[3]<<16));
    }
  }
}

// ---------------- q = h @ Wq + bq -> bf16 hi/lo ----------------
__global__ __launch_bounds__(128)
void qproj_kern(const float* __restrict__ h, const float* __restrict__ Wq,
                const float* __restrict__ bq,
                unsigned short* __restrict__ qh, unsigned short* __restrict__ ql){
  __shared__ float hs[128];
  const int v=blockIdx.x, c=threadIdx.x;
  hs[c]=h[(v<<7)+c];
  __syncthreads();
  float acc=bq[c];
  #pragma unroll 8
  for (int k=0;k<128;k++) acc=fmaf(hs[k],Wq[(k<<7)+c],acc);
  const unsigned short hi=f2bf(acc);
  qh[(v<<7)+c]=hi; ql[(v<<7)+c]=f2bf(acc-ubf(hi));
}

// ---------------- MFMA scores (main loop) ----------------
__global__ __launch_bounds__(256)
void scoresM_kern(const unsigned short* __restrict__ qh, const unsigned short* __restrict__ ql,
                  const unsigned short* __restrict__ Kh, const unsigned short* __restrict__ Kl,
                  unsigned short* __restrict__ Pb){
  const int t=threadIdx.x, w=t>>6, lane=t&63;
  const int v0=blockIdx.y*64;
  const int col=lane&31, kg=lane>>5;
  const int r0=v0+col;
  const size_t a0base=(size_t)r0*128, a1base=(size_t)(r0+32)*128;
  for (int ft=0; ft<4; ft++){
    const int fsub=blockIdx.x*512+(w+4*ft)*32;
    if (fsub>=NFP) break;
    const int f=fsub+col;
    const size_t bbase=(size_t)f*128;
    floatx16 acc0=fzero16(), acc1=fzero16();
    #pragma unroll
    for (int ks=0; ks<8; ks++){
      const int ko=ks*16+kg*8;
      short8 a0h=ld8(qh+a0base+ko), a0l=ld8(ql+a0base+ko);
      short8 a1h=ld8(qh+a1base+ko), a1l=ld8(ql+a1base+ko);
      short8 bh =ld8(Kh+bbase+ko),  bl =ld8(Kl+bbase+ko);
      acc0=MFMA32(a0h,bh,acc0,0,0,0);
      acc0=MFMA32(a0h,bl,acc0,0,0,0);
      acc0=MFMA32(a0l,bh,acc0,0,0,0);
      acc1=MFMA32(a1h,bh,acc1,0,0,0);
      acc1=MFMA32(a1h,bl,acc1,0,0,0);
      acc1=MFMA32(a1l,bh,acc1,0,0,0);
    }
    const bool inF=(f<NF);
    #pragma unroll
    for (int r=0;r<16;r++){
      const int rr=(r&3)+8*(r>>2)+4*kg;
      {
        const int row=v0+rr;
        const float s=acc0[r]*SCALE_QK;
        const float ep=inF? __expf(s):0.f;
        Pb[(size_t)row*NFP+f]=f2bf(ep);
      }
      {
        const int row=v0+32+rr;
        const float s=acc1[r]*SCALE_QK;
        const float ep=inF? __expf(s):0.f;
        Pb[(size_t)row*NFP+f]=f2bf(ep);
      }
    }
  }
}

// ---------------- MFMA PV (+ Z row-sums via ones-MFMA) ----------------
template<int SUMZ>
__global__ __launch_bounds__(256)
void pvM_kern(const unsigned short* __restrict__ Pb,
              const unsigned short* __restrict__ Vth, const unsigned short* __restrict__ Vtl,
              float* __restrict__ part, float* __restrict__ accg){
  __shared__ float Zs[64];
  const int t=threadIdx.x, w=t>>6, lane=t&63;
  const int slice=blockIdx.x, v0=blockIdx.y*64;
  const int col=lane&31, kg=lane>>5;
  const int d0=w*32;
  const int fbeg=slice*2048, fend=min(fbeg+2048,(int)NFP);
  if (SUMZ){ if (t<64) Zs[t]=0.f; __syncthreads(); }
  floatx16 acc0=fzero16(), acc1=fzero16(), z0=fzero16(), z1=fzero16();
  const short8 ones={(short)0x3F80,(short)0x3F80,(short)0x3F80,(short)0x3F80,
                     (short)0x3F80,(short)0x3F80,(short)0x3F80,(short)0x3F80};
  const unsigned short* pr0=Pb+(size_t)(v0+col)*NFP;
  const unsigned short* pr1=Pb+(size_t)(v0+32+col)*NFP;
  const unsigned short* vh =Vth+(size_t)(d0+col)*NFP;
  const unsigned short* vl =Vtl+(size_t)(d0+col)*NFP;
  for (int fc=fbeg; fc<fend; fc+=16){
    const int ko=fc+kg*8;
    short8 a0=ld8(pr0+ko), a1=ld8(pr1+ko);
    short8 bh=ld8(vh+ko),  bl=ld8(vl+ko);
    acc0=MFMA32(a0,bh,acc0,0,0,0);
    acc0=MFMA32(a0,bl,acc0,0,0,0);
    acc1=MFMA32(a1,bh,acc1,0,0,0);
    acc1=MFMA32(a1,bl,acc1,0,0,0);
    if (SUMZ && (((fc>>4)&3)==w)){
      z0=MFMA32(a0,ones,z0,0,0,0);
      z1=MFMA32(a1,ones,z1,0,0,0);
    }
  }
  const int d=d0+col;
  #pragma unroll
  for (int r=0;r<16;r++){
    const int rr=(r&3)+8*(r>>2)+4*kg;
    part[(((size_t)slice*NV+(v0+rr))<<7)+d]   =acc0[r];
    part[(((size_t)slice*NV+(v0+32+rr))<<7)+d]=acc1[r];
  }
  if (SUMZ){
    if (col==0){
      #pragma unroll
      for (int r=0;r<16;r++){
        const int rr=(r&3)+8*(r>>2)+4*kg;
        atomicAdd(&Zs[rr],z0[r]);
        atomicAdd(&Zs[32+rr],z1[r]);
      }
    }
    __syncthreads();
    if (t<64) atomicAdd(&accg[v0+t],Zs[t]);
  }
}

// ---------------- FINAL scores (SIMD fp32, runs once) ----------------
__global__ __launch_bounds__(256)
void scoresF_kern(const unsigned short* __restrict__ qh, const unsigned short* __restrict__ ql,
                  const unsigned short* __restrict__ Kh, const unsigned short* __restrict__ Kl,
                  const float* __restrict__ gum, unsigned short* __restrict__ Pb,
                  float* __restrict__ accg){
  __shared__ float As[32][68];
  __shared__ float Bs[32][132];
  __shared__ float Zs[64], Zls[64], Yps[64], Yls[64];
  const int t=threadIdx.x;
  const int f0=blockIdx.x*128;
  const int v0=blockIdx.y*64;
  float acc[4][8];
  #pragma unroll
  for(int i=0;i<4;i++){ for(int j=0;j<8;j++) acc[i][j]=0.f; }
  if (t<64){ Zs[t]=0.f; Zls[t]=0.f; Yps[t]=0.f; Yls[t]=0.f; }
  for (int kc=0;kc<128;kc+=32){
    { const int vloc=t>>2, koff=(t&3)*8;
      const size_t base=((size_t)(v0+vloc)<<7)+kc+koff;
      uint4 H=*(const uint4*)(qh+base), L=*(const uint4*)(ql+base);
      As[koff+0][vloc]=bflo(H.x)+bflo(L.x); As[koff+1][vloc]=bfhi(H.x)+bfhi(L.x);
      As[koff+2][vloc]=bflo(H.y)+bflo(L.y); As[koff+3][vloc]=bfhi(H.y)+bfhi(L.y);
      As[koff+4][vloc]=bflo(H.z)+bflo(L.z); As[koff+5][vloc]=bfhi(H.z)+bfhi(L.z);
      As[koff+6][vloc]=bflo(H.w)+bflo(L.w); As[koff+7][vloc]=bfhi(H.w)+bfhi(L.w); }
    { const int floc=t>>1, koff=(t&1)*16; const int f=f0+floc;
      const size_t base=((size_t)f<<7)+kc+koff;
      uint4 H0=*(const uint4*)(Kh+base), H1=*(const uint4*)(Kh+base+8);
      uint4 L0=*(const uint4*)(Kl+base), L1=*(const uint4*)(Kl+base+8);
      Bs[koff+0][floc]=bflo(H0.x)+bflo(L0.x); Bs[koff+1][floc]=bfhi(H0.x)+bfhi(L0.x);
      Bs[koff+2][floc]=bflo(H0.y)+bflo(L0.y); Bs[koff+3][floc]=bfhi(H0.y)+bfhi(L0.y);
      Bs[koff+4][floc]=bflo(H0.z)+bflo(L0.z); Bs[koff+5][floc]=bfhi(H0.z)+bfhi(L0.z);
      Bs[koff+6][floc]=bflo(H0.w)+bflo(L0.w); Bs[koff+7][floc]=bfhi(H0.w)+bfhi(L0.w);
      Bs[koff+8][floc]=bflo(H1.x)+bflo(L1.x); Bs[koff+9][floc]=bfhi(H1.x)+bfhi(L1.x);
      Bs[koff+10][floc]=bflo(H1.y)+bflo(L1.y); Bs[koff+11][floc]=bfhi(H1.y)+bfhi(L1.y);
      Bs[koff+12][floc]=bflo(H1.z)+bflo(L1.z); Bs[koff+13][floc]=bfhi(H1.z)+bfhi(L1.z);
      Bs[koff+14][floc]=bflo(H1.w)+bflo(L1.w); Bs[koff+15][floc]=bfhi(H1.w)+bfhi(L1.w); }
    __syncthreads();
    const int mloc=(t&15)*4, nloc=(t>>4)*8;
    #pragma unroll
    for (int kk=0;kk<32;kk++){
      const float4 a=*(const float4*)&As[kk][mloc];
      const float4 b0=*(const float4*)&Bs[kk][nloc];
      const float4 b1=*(const float4*)&Bs[kk][nloc+4];
      const float am[4]={a.x,a.y,a.z,a.w};
      const float bn[8]={b0.x,b0.y,b0.z,b0.w,b1.x,b1.y,b1.z,b1.w};
      #pragma unroll
      for(int mi=0;mi<4;mi++){
        #pragma unroll
        for(int ni=0;ni<8;ni++) acc[mi][ni]=fmaf(am[mi],bn[ni],acc[mi][ni]);
      }
    }
    __syncthreads();
  }
  const int mloc=(t&15)*4, nloc=(t>>4)*8;
  #pragma unroll
  for(int mi=0;mi<4;mi++){
    const int v=v0+mloc+mi;
    float zp=0.f, zl=0.f, yp=0.f, yl=0.f;
    float uu[8];
    { const int fbase=f0+nloc;
      if (fbase+8<=NF){
        const float* gsrc=gum+(size_t)v*NF+fbase;
        float4 g0=*(const float4*)gsrc, g1=*(const float4*)(gsrc+4);
        uu[0]=g0.x;uu[1]=g0.y;uu[2]=g0.z;uu[3]=g0.w;uu[4]=g1.x;uu[5]=g1.y;uu[6]=g1.z;uu[7]=g1.w;
      } else {
        for(int i=0;i<8;i++){ int f=fbase+i; uu[i]=(f<NF)? gum[(size_t)v*NF+f] : 0.5f; }
      } }
    unsigned short pr[8];
    #pragma unroll
    for(int ni=0;ni<8;ni++){
      const int f=f0+nloc+ni;
      const float s=acc[mi][ni]*SCALE_QK;
      float pv_=0.f;
      if (f<NF){
        const float ep=__expf(s);
        const float g=-__logf(-__logf(uu[ni]));
        const float el=__expf(2.0f*(s+g));
        pv_=el; zl+=el; yl+=el*s; zp+=ep; yp+=ep*s;
      }
      pr[ni]=f2bf(pv_);
    }
    uint4 pk;
    pk.x=(unsigned)pr[0]|((unsigned)pr[1]<<16);
    pk.y=(unsigned)pr[2]|((unsigned)pr[3]<<16);
    pk.z=(unsigned)pr[4]|((unsigned)pr[5]<<16);
    pk.w=(unsigned)pr[6]|((unsigned)pr[7]<<16);
    *(uint4*)(Pb+(size_t)v*NFP+f0+nloc)=pk;
    atomicAdd(&Zs[mloc+mi],zp);
    atomicAdd(&Zls[mloc+mi],zl); atomicAdd(&Yps[mloc+mi],yp); atomicAdd(&Yls[mloc+mi],yl);
  }
  __syncthreads();
  if (t<64){
    atomicAdd(&accg[v0+t],Zs[t]);
    atomicAdd(&accg[1024+v0+t],Zls[t]);
    atomicAdd(&accg[2048+v0+t],Yps[t]);
    atomicAdd(&accg[3072+v0+t],Yls[t]);
  }
}

// ---------------- main-loop gate update ----------------
__global__ __launch_bounds__(256)
void gate_kern(float* __restrict__ h, const float* __restrict__ part, const float* __restrict__ Z,
               const float* __restrict__ Wm1, const float* __restrict__ bm1,
               const float* __restrict__ Wm2, const float* __restrict__ bm2){
  const int t=threadIdx.x, w=t>>6, lane=t&63;
  const int v=(blockIdx.x<<2)+w;
  const float h0=h[(v<<7)+lane], h1=h[(v<<7)+64+lane];
  const float zr=1.0f/Z[v];
  float c0=0.f,c1=0.f;
  for (int s=0;s<NSLICE;s++){
    c0+=part[(((size_t)s*NV+v)<<7)+lane];
    c1+=part[(((size_t)s*NV+v)<<7)+64+lane];
  }
  c0*=zr; c1*=zr;
  float y0=bm1[lane], y1=bm1[64+lane];
  for (int k=0;k<64;k++){ const float a=__shfl(h0,k); y0=fmaf(a,Wm1[(k<<7)+lane],y0);      y1=fmaf(a,Wm1[(k<<7)+64+lane],y1); }
  for (int k=0;k<64;k++){ const float a=__shfl(h1,k); y0=fmaf(a,Wm1[((64+k)<<7)+lane],y0); y1=fmaf(a,Wm1[((64+k)<<7)+64+lane],y1); }
  for (int k=0;k<64;k++){ const float a=__shfl(c0,k); y0=fmaf(a,Wm1[((128+k)<<7)+lane],y0);y1=fmaf(a,Wm1[((128+k)<<7)+64+lane],y1); }
  for (int k=0;k<64;k++){ const float a=__shfl(c1,k); y0=fmaf(a,Wm1[((192+k)<<7)+lane],y0);y1=fmaf(a,Wm1[((192+k)<<7)+64+lane],y1); }
  y0=geluf(y0); y1=geluf(y1);
  float z0=bm2[lane], z1=bm2[64+lane];
  for (int k=0;k<64;k++){ const float a=__shfl(y0,k); z0=fmaf(a,Wm2[(k<<7)+lane],z0);      z1=fmaf(a,Wm2[(k<<7)+64+lane],z1); }
  for (int k=0;k<64;k++){ const float a=__shfl(y1,k); z0=fmaf(a,Wm2[((64+k)<<7)+lane],z0); z1=fmaf(a,Wm2[((64+k)<<7)+64+lane],z1); }
  const float g0=sigmf(z0), g1=sigmf(z1);
  h[(v<<7)+lane]   = fmaf(g0,c0-h0,h0);
  h[(v<<7)+64+lane]= fmaf(g1,c1-h1,h1);
}

// ---------------- cooc scan (persistent, 64 blocks x 1024 thr, MFMA gate) ----------------
// Per-atom schedule (barriers between phases):
//  S0: waves14-15: avgs from bufs; wave13(bid0): zero ALL 8 stripes of bufs[zz];
//      wave12: seedb=0,anyf=0; ALL waves: write own h row into X (bf16 hi/lo, swizzled)
//  S1: waves0-3: Y-GEMM (X @ Wc1_top via reg B-frags, hi/lo, 24 MFMA);
//      waves8-15: ypart = avg @ Wc1_bot (VALU from LDS W1b)
//  S2: waves0-3: Y = gelu(acc + ypart + bc1) -> LDS (bf16 hi/lo, swizzled)
//  S3: waves4-7: Z-GEMM (Y @ Wc2, 24 MFMA); G = sigmoid(Z+bc2) -> LDS
//  S4: ALL waves: h-update from G; seed atom a+1; grid barrier
__global__ __launch_bounds__(1024,4)
void cooc_kern(float* __restrict__ h, const int* __restrict__ cm, const float* __restrict__ cntf,
               const float* __restrict__ Wc1, const float* __restrict__ bc1,
               const float* __restrict__ Wc2, const float* __restrict__ bc2,
               float* __restrict__ bufs, unsigned* __restrict__ barr){
  __shared__ float W1b[128*128];                       // Wc1 rows 128..255 (avg part), 64KB
  __shared__ unsigned short Xh[32*128], Xl[32*128];    // h rows (16 used), swizzled
  __shared__ unsigned short Yh[32*128], Yl[32*128];    // gelu output, swizzled
  __shared__ float Gs[32*128];                         // sigmoid gates
  __shared__ float ypart2[4*128];
  __shared__ float avgs[128], seedb[128], bc1s[128], bc2s[128], cnts[64];
  __shared__ int anyf;
  const int t=threadIdx.x, w=t>>6, lane=t&63;
  const int bid=blockIdx.x;
  const int v=(bid<<4)+w;
  const int stripe=bid&7;
  const int col=lane&31, kg=lane>>5;

  // ---- one-time staging ----
  for (int i=t;i<128*128;i+=1024) W1b[i]=Wc1[16384+i];
  if (t<128){ bc1s[t]=bc1[t]; bc2s[t]=bc2[t]; }
  else if (t<192) cnts[t-128]=cntf[t-128];
  for (int i=2048+t;i<4096;i+=1024){ Xh[i]=0; Xl[i]=0; }   // zero X rows 16..31
  // ---- register B-fragments: waves0-3 Wc1_top tiles, waves4-7 Wc2 tiles ----
  short8 Bh[8], Bl[8];
  {
    const float* Wsrc=(w>=4&&w<8)? Wc2 : Wc1;
    const int n0=(w&3)*32;
    #pragma unroll
    for (int ks=0;ks<8;ks++){
      #pragma unroll
      for (int j=0;j<8;j++){
        const float x=Wsrc[(ks*16+kg*8+j)*128 + n0+col];
        const unsigned short hi=f2bf(x);
        Bh[ks][j]=(short)hi; Bl[ks][j]=(short)f2bf(x-ubf(hi));
      }
    }
  }
  const unsigned long long amask=__ballot(cm[lane*NV+v]!=0);
  float h0=h[(v<<7)+lane], h1=h[(v<<7)+64+lane];
  // ---- seed atom 0 (bufs pre-zeroed by host memset) ----
  if (t<128) seedb[t]=0.f;
  if (t==0) anyf=0;
  __syncthreads();
  if (amask&1ull){ atomicAdd(&seedb[lane],h0); atomicAdd(&seedb[64+lane],h1); if(lane==0) anyf=1; }
  __syncthreads();
  if (anyf && t<128) atomicAdd(&bufs[(stripe<<7)+t],seedb[t]);
  unsigned ep=0;
  gridbar2(barr,bid,t,++ep);

  for (int a=0;a<NA;a++){
    const int cur=a%3, nxt=(a+1)%3, zz=(a+2)%3;
    const float cf=cnts[a];
    // ---- S0 ----
    if (w>=14){
      const int i=t-896;
      float s=0.f;
      #pragma unroll
      for (int sp=0;sp<8;sp++)
        s+=__hip_atomic_load(&bufs[(cur<<10)+(sp<<7)+i],__ATOMIC_RELAXED,__HIP_MEMORY_SCOPE_AGENT);
      avgs[i]=s/fmaxf(cf,1.0f);
    } else if (w==13){
      if (bid==0){
        #pragma unroll
        for (int sp=0;sp<8;sp++){
          __hip_atomic_store(&bufs[(zz<<10)+(sp<<7)+lane],0.0f,__ATOMIC_RELAXED,__HIP_MEMORY_SCOPE_AGENT);
          __hip_atomic_store(&bufs[(zz<<10)+(sp<<7)+64+lane],0.0f,__ATOMIC_RELAXED,__HIP_MEMORY_SCOPE_AGENT);
        }
      }
    } else if (w==12){
      seedb[lane]=0.f; seedb[64+lane]=0.f;
      if (lane==0) anyf=0;
    }
    { // all waves: stage own h row (hi/lo, swizzle: ushort idx ^= (row&7)<<3)
      const unsigned short h0h=f2bf(h0), h1h=f2bf(h1);
      const unsigned short h0l=f2bf(h0-ubf(h0h)), h1l=f2bf(h1-ubf(h1h));
      const int sw=(w&7)<<3;
      Xh[(w<<7)+(lane^sw)]=h0h;      Xl[(w<<7)+(lane^sw)]=h0l;
      Xh[(w<<7)+((64+lane)^sw)]=h1h; Xl[(w<<7)+((64+lane)^sw)]=h1l;
    }
    __syncthreads();
    // ---- S1 ----
    floatx16 accY=fzero16();
    if (w<4){
      #pragma unroll
      for (int ks=0;ks<8;ks++){
        const int ko=ks*16+kg*8;
        const int ridx=(col<<7)+(ko^((col&7)<<3));
        short8 ah=ld8(&Xh[ridx]), al=ld8(&Xl[ridx]);
        accY=MFMA32(ah,Bh[ks],accY,0,0,0);
        accY=MFMA32(al,Bh[ks],accY,0,0,0);
        accY=MFMA32(ah,Bl[ks],accY,0,0,0);
      }
    } else if (w>=8){
      const int idx=t-512, ss=idx>>7, c2=idx&127;
      float acc=0.f;
      #pragma unroll
      for (int j=0;j<32;j++) acc=fmaf(avgs[ss*32+j],W1b[(ss*32+j)*128+c2],acc);
      ypart2[ss*128+c2]=acc;
    }
    __syncthreads();
    // ---- S2 ----
    if (w<4){
      const int c=(w<<5)+col;
      const float yav=ypart2[c]+ypart2[128+c]+ypart2[256+c]+ypart2[384+c]+bc1s[c];
      #pragma unroll
      for (int r=0;r<16;r++){
        const int rr=(r&3)+8*(r>>2)+4*kg;
        const float yv=geluf(accY[r]+yav);
        const unsigned short yh=f2bf(yv);
        const unsigned short yl=f2bf(yv-ubf(yh));
        const int wi=(rr<<7)+(c^((rr&7)<<3));
        Yh[wi]=yh; Yl[wi]=yl;
      }
    }
    __syncthreads();
    // ---- S3 ----
    if (w>=4&&w<8){
      floatx16 accZ=fzero16();
      #pragma unroll
      for (int ks=0;ks<8;ks++){
        const int ko=ks*16+kg*8;
        const int ridx=(col<<7)+(ko^((col&7)<<3));
        short8 ah=ld8(&Yh[ridx]), al=ld8(&Yl[ridx]);
        accZ=MFMA32(ah,Bh[ks],accZ,0,0,0);
        accZ=MFMA32(al,Bh[ks],accZ,0,0,0);
        accZ=MFMA32(ah,Bl[ks],accZ,0,0,0);
      }
      const int c=((w-4)<<5)+col;
      const float b2=bc2s[c];
      #pragma unroll
      for (int r=0;r<16;r++){
        const int rr=(r&3)+8*(r>>2)+4*kg;
        Gs[(rr<<7)+c]=sigmf(accZ[r]+b2);
      }
    }
    __syncthreads();
    // ---- S4 ----
    {
      const bool act=((amask>>a)&1ull)&&(cf>=2.0f);
      if (act){
        const float g0=Gs[(w<<7)+lane], g1=Gs[(w<<7)+64+lane];
        h0=fmaf(g0,avgs[lane]-h0,h0);
        h1=fmaf(g1,avgs[64+lane]-h1,h1);
      }
    }
    if (a<NA-1){
      if ((amask>>(a+1))&1ull){
        atomicAdd(&seedb[lane],h0); atomicAdd(&seedb[64+lane],h1);
        if (lane==0) anyf=1;
      }
      __syncthreads();
      if (anyf && t<128)
        atomicAdd(&bufs[(nxt<<10)+(stripe<<7)+t],seedb[t]);
      gridbar2(barr,bid,t,++ep);
    }
  }
  h[(v<<7)+lane]=h0; h[(v<<7)+64+lane]=h1;
}

// ---------------- final write-out ----------------
__global__ __launch_bounds__(256)
void writeout_kern(const float* __restrict__ accg, const float* __restrict__ part,
                   float* __restrict__ out){
  const int b=blockIdx.x, t=threadIdx.x;
  const int v0=b*16;
  for (int i=t;i<16*128;i+=256){
    const int v=v0+(i>>7), d=i&127;
    float s=0.f;
    for (int sl=0;sl<NSLICE;sl++) s+=part[(((size_t)sl*NV+v)<<7)+d];
    out[1+((size_t)v<<7)+d]=s/accg[1024+v];
  }
  __shared__ float es[16], hsv[16];
  if (t<16){
    const int v=v0+t;
    const float Zp=accg[v], Zl=accg[1024+v], Yp=accg[2048+v], Yl=accg[3072+v];
    es[t]=-Yl/Zl;
    hsv[t]=-(Yp/Zp-logf(Zp));
  }
  __syncthreads();
  if (t==0){
    float a=0.f,c=0.f;
    for(int i=0;i<16;i++){ a+=es[i]; c+=hsv[i]; }
    atomicAdd(&out[0],a);
    atomicAdd(&out[1+(size_t)NV*128],c);
  }
}

// ---------------- host ----------------
extern "C" void kernel_launch(void* const* d_in, const int* in_sizes, int n_in,
                              void* d_out, int out_size, void* d_ws, size_t ws_size,
                              hipStream_t stream){
  (void)in_sizes; (void)n_in; (void)ws_size;
  const float* fe =(const float*)d_in[0];
  const float* vi =(const float*)d_in[1];
  const int*   cm =(const int*)  d_in[2];
  const float* gum=(const float*)d_in[3];
  const float* Wq =(const float*)d_in[4];  const float* bq =(const float*)d_in[5];
  const float* Wk =(const float*)d_in[6];  const float* bk =(const float*)d_in[7];
  const float* Wv =(const float*)d_in[8];  const float* bv =(const float*)d_in[9];
  const float* Wm1=(const float*)d_in[10]; const float* bm1=(const float*)d_in[11];
  const float* Wm2=(const float*)d_in[12]; const float* bm2=(const float*)d_in[13];
  const float* Wc1=(const float*)d_in[14]; const float* bc1=(const float*)d_in[15];
  const float* Wc2=(const float*)d_in[16]; const float* bc2=(const float*)d_in[17];
  float* out=(float*)d_out;
  char* w8=(char*)d_ws;
  unsigned short* Kh =(unsigned short*)(w8+OFF_KH);
  unsigned short* Kl =(unsigned short*)(w8+OFF_KL);
  unsigned short* Vth=(unsigned short*)(w8+OFF_VTH);
  unsigned short* Vtl=(unsigned short*)(w8+OFF_VTL);
  unsigned short* Pb =(unsigned short*)(w8+OFF_P);
  float* hb  =(float*)(w8+OFF_H);
  unsigned short* qhb=(unsigned short*)(w8+OFF_QH);
  unsigned short* qlb=(unsigned short*)(w8+OFF_QL);
  float* part=(float*)(w8+OFF_PART);
  float* accb=(float*)(w8+OFF_ACC);
  float* avgb=accb+4096;
  float* cntf=(float*)(w8+OFF_CNT);
  unsigned* barr=(unsigned*)(w8+OFF_P);   // overlays dead-at-cooc-time P head

  hipMemsetAsync(out,0,(size_t)out_size*4,stream);
  hipMemcpyAsync(hb,vi,(size_t)NV*128*4,hipMemcpyDeviceToDevice,stream);
  cnt_kern<<<NA,256,0,stream>>>(cm,cntf);
  kvproj_kern<<<dim3(NFP/64,2),256,0,stream>>>(fe,Wk,bk,Wv,bv,Kh,Kl,Vth,Vtl);

  for (int it=0; it<3; it++){
    hipMemsetAsync(accb,0,28672,stream);
    qproj_kern<<<NV,128,0,stream>>>(hb,Wq,bq,qhb,qlb);
    scoresM_kern<<<dim3(98,16),256,0,stream>>>(qhb,qlb,Kh,Kl,Pb);
    pvM_kern<1><<<dim3(NSLICE,16),256,0,stream>>>(Pb,Vth,Vtl,part,accb);
    gate_kern<<<NV/4,256,0,stream>>>(hb,part,accb,Wm1,bm1,Wm2,bm2);
    hipMemsetAsync(barr,0,2304,stream);
    cooc_kern<<<64,1024,0,stream>>>(hb,cm,cntf,Wc1,bc1,Wc2,bc2,avgb,barr);
  }

  hipMemsetAsync(accb,0,28672,stream);
  qproj_kern<<<NV,128,0,stream>>>(hb,Wq,bq,qhb,qlb);
  scoresF_kern<<<dim3(NFP/128,16),256,0,stream>>>(qhb,qlb,Kh,Kl,gum,Pb,accb);
  pvM_kern<0><<<dim3(NSLICE,16),256,0,stream>>>(Pb,Vth,Vtl,part,accb);
  writeout_kern<<<64,256,0,stream>>>(accb,part,out);
}